// Round 4
// baseline (1508.340 us; speedup 1.0000x reference)
//
#include <hip/hip_runtime.h>
#include <math.h>

#define NV 163842
#define NE 983052
#define NBE 3841   // ceil(NE/256)

// order-preserving float->uint transform (descending top-k: larger value -> larger key)
static __device__ __forceinline__ unsigned ordf(float f){
  unsigned u = __float_as_uint(f);
  return (u & 0x80000000u) ? ~u : (u | 0x80000000u);
}

// ---------------- CSR build ----------------

__global__ void deg_count(const int* __restrict__ dst, const int* __restrict__ cnt,
                          int m_static, int* __restrict__ degi){
  int m = cnt ? cnt[0] : m_static;
  int stride = gridDim.x*blockDim.x;
  for(int e = blockIdx.x*blockDim.x+threadIdx.x; e<m; e+=stride)
    atomicAdd(&degi[dst[e]], 1);
}

// per-256-block sums of degi
__global__ void block_sums(const int* __restrict__ degi, int n, int* __restrict__ bsum){
  int i = blockIdx.x*256 + threadIdx.x;
  int v = (i<n) ? degi[i] : 0;
  for(int o=32;o;o>>=1) v += __shfl_down(v,o,64);
  __shared__ int sg[4];
  int lane=threadIdx.x&63, w=threadIdx.x>>6;
  if(lane==0) sg[w]=v;
  __syncthreads();
  if(threadIdx.x==0) bsum[blockIdx.x]=sg[0]+sg[1]+sg[2]+sg[3];
}

// in-place exclusive scan of bsum[0..nb), single block, chunked LDS scan
__global__ void scan_bsums(int* __restrict__ bsum, int nb){
  __shared__ int sh[256];
  __shared__ int carry;
  if(threadIdx.x==0) carry=0;
  __syncthreads();
  for(int base=0;base<nb;base+=256){
    int i = base+threadIdx.x;
    int v = (i<nb) ? bsum[i] : 0;
    sh[threadIdx.x]=v;
    __syncthreads();
    for(int o=1;o<256;o<<=1){
      int t = (threadIdx.x>=o) ? sh[threadIdx.x-o] : 0;
      __syncthreads();
      sh[threadIdx.x]+=t;
      __syncthreads();
    }
    int incl = sh[threadIdx.x];
    int c = carry;
    if(i<nb) bsum[i] = incl - v + c;
    __syncthreads();
    if(threadIdx.x==255) carry = c + incl;
    __syncthreads();
  }
}

// rowptr[i] = exclusive scan of degi (+ block offset); also cursor copy and dinv
__global__ void scan_local(const int* __restrict__ degi, const int* __restrict__ bofs,
                           int n, int* __restrict__ rowptr, int* __restrict__ cursor,
                           float* __restrict__ dinv){
  __shared__ int sh[256];
  int i = blockIdx.x*256 + threadIdx.x;
  int v = (i<n) ? degi[i] : 0;
  sh[threadIdx.x]=v;
  __syncthreads();
  for(int o=1;o<256;o<<=1){
    int t = (threadIdx.x>=o) ? sh[threadIdx.x-o] : 0;
    __syncthreads();
    sh[threadIdx.x]+=t;
    __syncthreads();
  }
  if(i<n){
    int excl = sh[threadIdx.x] - v + bofs[blockIdx.x];
    rowptr[i]=excl; cursor[i]=excl;
    dinv[i] = rsqrtf((float)v + 1.0f);
  }
}

__global__ void csr_fill(const int* __restrict__ src, const int* __restrict__ dst,
                         const int* __restrict__ cnt, int m_static,
                         int* __restrict__ cursor, int* __restrict__ csr){
  int m = cnt ? cnt[0] : m_static;
  int stride = gridDim.x*blockDim.x;
  for(int e = blockIdx.x*blockDim.x+threadIdx.x; e<m; e+=stride){
    int pos = atomicAdd(&cursor[dst[e]], 1);
    csr[pos] = src[e];
  }
}

// g[d,f] = dinv[d] * ( h[d,f]*dinv[d] + sum_{s in N(d)} h[s,f]*dinv[s] )
__global__ void csr_gather(const float* __restrict__ h, const float* __restrict__ dinv,
                           const int* __restrict__ rowptr, const int* __restrict__ degi,
                           const int* __restrict__ csr, float* __restrict__ g,
                           int n, int Fi, int fshift){
  long long t = (long long)blockIdx.x*blockDim.x + threadIdx.x;
  int d = (int)(t>>fshift);
  if(d>=n) return;
  int f = (int)t & (Fi-1);
  int start = rowptr[d], deg = degi[d];
  float di = dinv[d];
  float acc = h[(size_t)d*Fi+f]*di;   // self-loop term (pre di scale)
  for(int j=0;j<deg;j++){
    int s = csr[start+j];
    acc = fmaf(h[(size_t)s*Fi+f], dinv[s], acc);
  }
  g[t] = acc*di;
}

// ---------------- dense pieces ----------------

// hfull = relu(g @ W + b); thread computes one output column for 16 consecutive rows
__global__ void matmul_relu(const float* __restrict__ h, const float* __restrict__ W,
                            const float* __restrict__ b, float* __restrict__ out,
                            int n, int Fi, int Fo, int shift){
  long long t = (long long)blockIdx.x*blockDim.x + threadIdx.x;
  int c = (int)(t & (Fo-1));
  int rb = (int)(t >> shift) * 16;
  if(rb >= n) return;
  float acc[16];
  #pragma unroll
  for(int j=0;j<16;j++) acc[j]=0.f;
  int rows = n - rb; if(rows>16) rows=16;
  if(rows==16){
    for(int i=0;i<Fi;i++){
      float w = W[(size_t)i*Fo + c];
      const float* hp = h + (size_t)rb*Fi + i;
      #pragma unroll
      for(int j=0;j<16;j++) acc[j] = fmaf(hp[(size_t)j*Fi], w, acc[j]);
    }
  } else {
    for(int i=0;i<Fi;i++){
      float w = W[(size_t)i*Fo + c];
      const float* hp = h + (size_t)rb*Fi + i;
      for(int j=0;j<rows;j++) acc[j] = fmaf(hp[(size_t)j*Fi], w, acc[j]);
    }
  }
  float bc = b[c];
  for(int j=0;j<rows;j++){
    float v = acc[j] + bc;
    out[(size_t)(rb+j)*Fo + c] = v>0.f ? v : 0.f;
  }
}

// score[i] = tanh((h[i,:].p) * rsqrt(p.p)); 4 rows per block
__global__ void score2(const float* __restrict__ h, int n, int F,
                       const float* __restrict__ p, float* __restrict__ score){
  __shared__ float red[4];
  __shared__ float pninv;
  float pe = (threadIdx.x < F) ? p[threadIdx.x] : 0.f;
  float s = pe*pe;
  for(int o=32;o;o>>=1) s += __shfl_down(s,o,64);
  int lane=threadIdx.x&63, w=threadIdx.x>>6;
  if(lane==0) red[w]=s;
  __syncthreads();
  if(threadIdx.x==0) pninv = rsqrtf(red[0]+red[1]+red[2]+red[3]);
  __syncthreads();
  int wid = blockIdx.x*4 + w;
  if(wid>=n) return;
  const float* row = h + (size_t)wid*F;
  float d=0.f;
  for(int f=lane; f<F; f+=64) d = fmaf(row[f], p[f], d);
  for(int o=32;o;o>>=1) d += __shfl_down(d,o,64);
  if(lane==0) score[wid] = tanhf(d*pninv);
}

// exact k-th largest via 4-pass byte radix select with ballot-aggregated LDS histogram
// (tanh scores concentrate the exponent byte into ~4 bins -> per-element LDS atomics
//  would serialize; aggregate equal keys within each wave first: 8 ballots -> match mask)
__global__ void radix_select(const float* __restrict__ score, int n, int k,
                             unsigned* __restrict__ out_thr, int* __restrict__ out_q){
  __shared__ int hist[256];
  __shared__ unsigned pref;
  __shared__ int rank;
  if(threadIdx.x==0){ pref=0u; rank=k; }
  __syncthreads();
  int lane = threadIdx.x & 63;
  for(int b=3;b>=0;b--){
    if(threadIdx.x<256) hist[threadIdx.x]=0;
    __syncthreads();
    unsigned p = pref;
    for(int i=threadIdx.x;i<n;i+=blockDim.x){
      unsigned o = ordf(score[i]);
      bool act = (b==3) || (((o ^ p) >> ((b+1)*8)) == 0);
      unsigned key = (o>>(b*8))&255u;
      unsigned long long eq = __ballot(act);
      #pragma unroll
      for(int bit=0;bit<8;bit++){
        unsigned long long bb = __ballot(act && ((key>>bit)&1u));
        eq &= ((key>>bit)&1u) ? bb : ~bb;
      }
      if(act){
        int lead = __ffsll((unsigned long long)eq) - 1;
        if(lane==lead) atomicAdd(&hist[key], __popcll(eq));
      }
    }
    __syncthreads();
    if(threadIdx.x==0){
      int running=0; int d;
      for(d=255;d>0;d--){
        if(running + hist[d] >= rank) break;
        running += hist[d];
      }
      pref |= ((unsigned)d) << (b*8);
      rank -= running;
    }
    __syncthreads();
  }
  if(threadIdx.x==0){ out_thr[0]=pref; out_q[0]=rank; }
}

__global__ void sel_blockcount(const float* __restrict__ score, int n,
                               const unsigned* __restrict__ thr,
                               int* __restrict__ blkGt, int* __restrict__ blkEq){
  int i = blockIdx.x*256 + threadIdx.x;
  unsigned vthr = thr[0];
  int gt=0, eq=0;
  if(i<n){ unsigned o=ordf(score[i]); gt = (o>vthr); eq = (o==vthr); }
  unsigned long long bg=__ballot(gt), be=__ballot(eq);
  __shared__ int sg[4], se[4];
  int lane=threadIdx.x&63, w=threadIdx.x>>6;
  if(lane==0){ sg[w]=__popcll(bg); se[w]=__popcll(be); }
  __syncthreads();
  if(threadIdx.x==0){
    int g=0,e=0;
    for(int j=0;j<4;j++){ g+=sg[j]; e+=se[j]; }
    blkGt[blockIdx.x]=g; blkEq[blockIdx.x]=e;
  }
}

// parallel exclusive scan of the two per-block count arrays (nb <= 641)
__global__ void scan_pair(int* __restrict__ blkGt, int* __restrict__ blkEq, int nb){
  __shared__ int shg[256], she[256];
  __shared__ int cg, ce;
  if(threadIdx.x==0){ cg=0; ce=0; }
  __syncthreads();
  for(int base=0;base<nb;base+=256){
    int i = base+threadIdx.x;
    int vg = (i<nb)?blkGt[i]:0;
    int ve = (i<nb)?blkEq[i]:0;
    shg[threadIdx.x]=vg; she[threadIdx.x]=ve;
    __syncthreads();
    for(int o=1;o<256;o<<=1){
      int tg = (threadIdx.x>=o)?shg[threadIdx.x-o]:0;
      int te = (threadIdx.x>=o)?she[threadIdx.x-o]:0;
      __syncthreads();
      shg[threadIdx.x]+=tg; she[threadIdx.x]+=te;
      __syncthreads();
    }
    int ig = shg[threadIdx.x], ie = she[threadIdx.x];
    int c0=cg, c1=ce;
    if(i<nb){ blkGt[i]=ig-vg+c0; blkEq[i]=ie-ve+c1; }
    __syncthreads();
    if(threadIdx.x==255){ cg=c0+ig; ce=c1+ie; }
    __syncthreads();
  }
}

__global__ void compact(const float* __restrict__ score, int n,
                        const unsigned* __restrict__ thr, const int* __restrict__ qp,
                        const int* __restrict__ blkGt, const int* __restrict__ blkEq,
                        int* __restrict__ newidx, int* __restrict__ oldidx){
  int i = blockIdx.x*256 + threadIdx.x;
  unsigned vthr = thr[0];
  int q = qp[0];
  int gt=0, eq=0;
  if(i<n){ unsigned o=ordf(score[i]); gt=(o>vthr); eq=(o==vthr); }
  unsigned long long bg=__ballot(gt), be=__ballot(eq);
  int lane=threadIdx.x&63, w=threadIdx.x>>6;
  unsigned long long mask = lane ? (~0ull >> (64-lane)) : 0ull;
  int pg = __popcll(bg & mask), pe = __popcll(be & mask);
  __shared__ int sg[4], se[4];
  if(lane==63){ sg[w]=pg+gt; se[w]=pe+eq; }
  __syncthreads();
  int wg=0,we=0;
  for(int j=0;j<w;j++){ wg+=sg[j]; we+=se[j]; }
  if(i<n){
    int gtp = blkGt[blockIdx.x] + wg + pg;
    int eqp = blkEq[blockIdx.x] + we + pe;
    int sel = gt || (eq && (eqp < q));
    if(sel){
      int pos = gtp + (eqp < q ? eqp : q);  // rank among selected, by original index
      newidx[i]=pos; oldidx[pos]=i;
    } else newidx[i]=-1;
  }
}

__global__ void gather_scale(const float* __restrict__ hfull, const float* __restrict__ score,
                             const int* __restrict__ oldidx, float* __restrict__ hout,
                             int k, int Fo, int shift){
  long long t = (long long)blockIdx.x*blockDim.x + threadIdx.x;
  int nr = (int)(t >> shift);
  if(nr >= k) return;
  int f = (int)(t & (Fo-1));
  int old = oldidx[nr];
  hout[t] = hfull[(size_t)old*Fo+f] * score[old];
}

// ---------------- scan-based edge compaction (no same-address atomics) ----------------

__global__ void edge_valid_count(const int* __restrict__ src, const int* __restrict__ dst,
                                 const int* __restrict__ cnt_in, int m_static,
                                 const int* __restrict__ newidx, int* __restrict__ bcnt){
  int m = cnt_in ? cnt_in[0] : m_static;
  int i = blockIdx.x*256 + threadIdx.x;
  int v = 0;
  if(i<m) v = (newidx[src[i]]>=0 && newidx[dst[i]]>=0);
  unsigned long long b = __ballot(v);
  __shared__ int sg[4];
  int lane=threadIdx.x&63, w=threadIdx.x>>6;
  if(lane==0) sg[w]=__popcll(b);
  __syncthreads();
  if(threadIdx.x==0) bcnt[blockIdx.x]=sg[0]+sg[1]+sg[2]+sg[3];
}

// exclusive scan of bcnt[0..nb) in place; total -> cnt_out[0]
__global__ void edge_scan(int* __restrict__ bcnt, int nb, int* __restrict__ cnt_out){
  __shared__ int sh[256];
  __shared__ int carry;
  if(threadIdx.x==0) carry=0;
  __syncthreads();
  for(int base=0;base<nb;base+=256){
    int i = base+threadIdx.x;
    int v = (i<nb) ? bcnt[i] : 0;
    sh[threadIdx.x]=v;
    __syncthreads();
    for(int o=1;o<256;o<<=1){
      int t = (threadIdx.x>=o) ? sh[threadIdx.x-o] : 0;
      __syncthreads();
      sh[threadIdx.x]+=t;
      __syncthreads();
    }
    int incl = sh[threadIdx.x];
    int c = carry;
    if(i<nb) bcnt[i] = incl - v + c;
    __syncthreads();
    if(threadIdx.x==255) carry = c + incl;
    __syncthreads();
  }
  if(threadIdx.x==0) cnt_out[0]=carry;
}

__global__ void edge_write(const int* __restrict__ src, const int* __restrict__ dst,
                           const int* __restrict__ cnt_in, int m_static,
                           const int* __restrict__ newidx, const int* __restrict__ bofs,
                           int* __restrict__ osrc, int* __restrict__ odst){
  int m = cnt_in ? cnt_in[0] : m_static;
  int i = blockIdx.x*256 + threadIdx.x;
  int v=0, ns=0, nd=0;
  if(i<m){
    ns = newidx[src[i]]; nd = newidx[dst[i]];
    v = (ns>=0 && nd>=0);
  }
  unsigned long long b = __ballot(v);
  int lane=threadIdx.x&63, w=threadIdx.x>>6;
  unsigned long long mask = lane ? (~0ull >> (64-lane)) : 0ull;
  int p = __popcll(b & mask);
  __shared__ int sg[4];
  if(lane==63) sg[w]=p+v;
  __syncthreads();
  int wofs=0;
  for(int j=0;j<w;j++) wofs+=sg[j];
  if(v){
    int pos = bofs[blockIdx.x] + wofs + p;
    osrc[pos]=ns; odst[pos]=nd;
  }
}

// ---------------- epilogue ----------------

// per-feature max & mean over final nodes; xc[0:256]=max, xc[256:512]=mean
__global__ void pool_kernel(const float* __restrict__ h, int n, float* __restrict__ xc){
  int f = blockIdx.x;
  float mx = -3.402823466e38f, sm=0.f;
  for(int r=threadIdx.x; r<n; r+=blockDim.x){
    float v = h[(size_t)r*256+f];
    mx = fmaxf(mx,v); sm += v;
  }
  __shared__ float smx[4], ssm[4];
  for(int o=32;o;o>>=1){ mx=fmaxf(mx,__shfl_down(mx,o,64)); sm+=__shfl_down(sm,o,64); }
  int lane=threadIdx.x&63, w=threadIdx.x>>6;
  if(lane==0){ smx[w]=mx; ssm[w]=sm; }
  __syncthreads();
  if(threadIdx.x==0){
    for(int j=1;j<4;j++){ mx=fmaxf(mx,smx[j]); sm+=ssm[j]; }
    xc[f]=mx; xc[256+f]=sm/(float)n;
  }
}

__global__ void fc_kernel(const float* __restrict__ xc, const float* __restrict__ fcw,
                          const float* __restrict__ fcb, const float* __restrict__ fc2w,
                          const float* __restrict__ fc2b, float* __restrict__ out){
  __shared__ float x[512];
  for(int i=threadIdx.x;i<512;i+=256) x[i]=xc[i];
  __syncthreads();
  int j=threadIdx.x;
  float a=fcb[j];
  for(int i=0;i<512;i++) a = fmaf(x[i], fcw[(size_t)j*512+i], a);
  a = a>0.f ? a : 0.f;
  float v = a*fc2w[j];
  for(int o=32;o;o>>=1) v += __shfl_down(v,o,64);
  __shared__ float sv[4];
  int lane=threadIdx.x&63, w=threadIdx.x>>6;
  if(lane==0) sv[w]=v;
  __syncthreads();
  if(threadIdx.x==0) out[0]=sv[0]+sv[1]+sv[2]+sv[3]+fc2b[0];
}

extern "C" void kernel_launch(void* const* d_in, const int* in_sizes, int n_in,
                              void* d_out, int out_size, void* d_ws, size_t ws_size,
                              hipStream_t stream) {
  const float* x   = (const float*)d_in[0];
  const int*   ei  = (const int*)d_in[1];
  const float* Wm[4] = {(const float*)d_in[2],(const float*)d_in[5],(const float*)d_in[8],(const float*)d_in[11]};
  const float* bv[4] = {(const float*)d_in[3],(const float*)d_in[6],(const float*)d_in[9],(const float*)d_in[12]};
  const float* pv[4] = {(const float*)d_in[4],(const float*)d_in[7],(const float*)d_in[10],(const float*)d_in[13]};
  const float* fcw  = (const float*)d_in[14];
  const float* fcb  = (const float*)d_in[15];
  const float* fc2w = (const float*)d_in[16];
  const float* fc2b = (const float*)d_in[17];

  char* base = (char*)d_ws; size_t off=0;
  auto alloc = [&](size_t bytes)->void*{
    void* p = base + off; off += (bytes + 511) & ~(size_t)511; return p;
  };
  int*   es1    = (int*)  alloc((size_t)NE*4);
  int*   ed1    = (int*)  alloc((size_t)NE*4);
  int*   es2    = (int*)  alloc((size_t)NE*4);
  int*   ed2    = (int*)  alloc((size_t)NE*4);
  int*   csr    = (int*)  alloc((size_t)NE*4);
  int*   degi   = (int*)  alloc((size_t)NV*4);
  int*   rowptr = (int*)  alloc((size_t)NV*4);
  int*   cursor = (int*)  alloc((size_t)NV*4);
  float* dinv   = (float*)alloc((size_t)NV*4);
  float* score  = (float*)alloc((size_t)NV*4);
  int*   newidx = (int*)  alloc((size_t)NV*4);
  int*   oldidx = (int*)  alloc((size_t)NV*4);
  float* g      = (float*)alloc((size_t)2621568*4);
  float* hfull  = (float*)alloc((size_t)5243136*4);
  float* hbuf   = (float*)alloc((size_t)2621696*4);
  int*   bsum   = (int*)  alloc(4096);
  int*   ebcnt  = (int*)  alloc((size_t)NBE*4+512);
  int*   cnt    = (int*)  alloc(64);
  unsigned* thr = (unsigned*)alloc(64);
  int*   qv     = (int*)  alloc(64);
  int*   blkGt  = (int*)  alloc(4096);
  int*   blkEq  = (int*)  alloc(4096);
  float* xc     = (float*)alloc(2048);
  if (off > ws_size) return;

  const int ns[5]   = {163842, 81921, 40961, 20481, 10241};
  const int dims[5] = {4, 32, 64, 128, 256};
  const int foshf[4]= {5, 6, 7, 8};     // log2(Fo)
  const int fishf[4]= {2, 5, 6, 7};     // log2(Fi)

  const int* curS[4] = {ei,      es1, es2, es1};
  const int* curD[4] = {ei + NE, ed1, ed2, ed1};
  int*       outS[3] = {es1, es2, es1};
  int*       outD[3] = {ed1, ed2, ed1};

  const float* hin = x;
  for(int l=0;l<4;l++){
    int n=ns[l], k=ns[l+1], Fi=dims[l], Fo=dims[l+1];
    const int* cin = (l==0) ? nullptr : (cnt + (l-1));
    int nb = (n+255)/256;
    // ---- CSR build ----
    hipMemsetAsync(degi, 0, (size_t)n*4, stream);
    unsigned egrid = (l==0) ? 2048 : 1024;
    deg_count<<<egrid,256,0,stream>>>(curD[l], cin, NE, degi);
    block_sums<<<nb,256,0,stream>>>(degi, n, bsum);
    scan_bsums<<<1,256,0,stream>>>(bsum, nb);
    scan_local<<<nb,256,0,stream>>>(degi, bsum, n, rowptr, cursor, dinv);
    csr_fill<<<egrid,256,0,stream>>>(curS[l], curD[l], cin, NE, cursor, csr);
    // ---- aggregation (gather, no atomics) ----
    long long nf = (long long)n*Fi;
    csr_gather<<<(unsigned)((nf+255)/256),256,0,stream>>>(hin, dinv, rowptr, degi, csr, g, n, Fi, fishf[l]);
    // ---- dense: hfull = relu(g@W + b) ----
    long long rbc = (n+15)/16;
    matmul_relu<<<(unsigned)((rbc*Fo+255)/256),256,0,stream>>>(g, Wm[l], bv[l], hfull, n, Fi, Fo, foshf[l]);
    // ---- top-k pooling ----
    score2<<<(n+3)/4,256,0,stream>>>(hfull, n, Fo, pv[l], score);
    radix_select<<<1,1024,0,stream>>>(score, n, k, thr, qv);
    sel_blockcount<<<nb,256,0,stream>>>(score, n, thr, blkGt, blkEq);
    scan_pair<<<1,256,0,stream>>>(blkGt, blkEq, nb);
    compact<<<nb,256,0,stream>>>(score, n, thr, qv, blkGt, blkEq, newidx, oldidx);
    gather_scale<<<(unsigned)((((long long)k*Fo)+255)/256),256,0,stream>>>(hfull, score, oldidx, hbuf, k, Fo, foshf[l]);
    // ---- edge compaction for next layer (deterministic scan, no hot atomics) ----
    if(l<3){
      edge_valid_count<<<NBE,256,0,stream>>>(curS[l], curD[l], cin, NE, newidx, ebcnt);
      edge_scan<<<1,256,0,stream>>>(ebcnt, NBE, cnt + l);
      edge_write<<<NBE,256,0,stream>>>(curS[l], curD[l], cin, NE, newidx, ebcnt, outS[l], outD[l]);
    }
    hin = hbuf;
  }

  pool_kernel<<<256,256,0,stream>>>(hbuf, ns[4], xc);
  fc_kernel<<<1,256,0,stream>>>(xc, fcw, fcb, fc2w, fc2b, (float*)d_out);
}

// Round 5
// 927.744 us; speedup vs baseline: 1.6258x; 1.6258x over previous
//
#include <hip/hip_runtime.h>
#include <math.h>

#define NV 163842
#define NE 983052
#define NBE 3841   // ceil(NE/256)

// order-preserving float->uint transform (descending top-k: larger value -> larger key)
static __device__ __forceinline__ unsigned ordf(float f){
  unsigned u = __float_as_uint(f);
  return (u & 0x80000000u) ? ~u : (u | 0x80000000u);
}

// ---------------- CSR build ----------------

__global__ void deg_count(const int* __restrict__ dst, const int* __restrict__ cnt,
                          int m_static, int* __restrict__ degi){
  int m = cnt ? cnt[0] : m_static;
  int stride = gridDim.x*blockDim.x;
  for(int e = blockIdx.x*blockDim.x+threadIdx.x; e<m; e+=stride)
    atomicAdd(&degi[dst[e]], 1);
}

// per-256-block sums of degi
__global__ void block_sums(const int* __restrict__ degi, int n, int* __restrict__ bsum){
  int i = blockIdx.x*256 + threadIdx.x;
  int v = (i<n) ? degi[i] : 0;
  for(int o=32;o;o>>=1) v += __shfl_down(v,o,64);
  __shared__ int sg[4];
  int lane=threadIdx.x&63, w=threadIdx.x>>6;
  if(lane==0) sg[w]=v;
  __syncthreads();
  if(threadIdx.x==0) bsum[blockIdx.x]=sg[0]+sg[1]+sg[2]+sg[3];
}

// in-place exclusive scan of bsum[0..nb), single block, chunked LDS scan
__global__ void scan_bsums(int* __restrict__ bsum, int nb){
  __shared__ int sh[256];
  __shared__ int carry;
  if(threadIdx.x==0) carry=0;
  __syncthreads();
  for(int base=0;base<nb;base+=256){
    int i = base+threadIdx.x;
    int v = (i<nb) ? bsum[i] : 0;
    sh[threadIdx.x]=v;
    __syncthreads();
    for(int o=1;o<256;o<<=1){
      int t = (threadIdx.x>=o) ? sh[threadIdx.x-o] : 0;
      __syncthreads();
      sh[threadIdx.x]+=t;
      __syncthreads();
    }
    int incl = sh[threadIdx.x];
    int c = carry;
    if(i<nb) bsum[i] = incl - v + c;
    __syncthreads();
    if(threadIdx.x==255) carry = c + incl;
    __syncthreads();
  }
}

// rowptr[i] = exclusive scan of degi (+ block offset); also cursor copy and dinv
__global__ void scan_local(const int* __restrict__ degi, const int* __restrict__ bofs,
                           int n, int* __restrict__ rowptr, int* __restrict__ cursor,
                           float* __restrict__ dinv){
  __shared__ int sh[256];
  int i = blockIdx.x*256 + threadIdx.x;
  int v = (i<n) ? degi[i] : 0;
  sh[threadIdx.x]=v;
  __syncthreads();
  for(int o=1;o<256;o<<=1){
    int t = (threadIdx.x>=o) ? sh[threadIdx.x-o] : 0;
    __syncthreads();
    sh[threadIdx.x]+=t;
    __syncthreads();
  }
  if(i<n){
    int excl = sh[threadIdx.x] - v + bofs[blockIdx.x];
    rowptr[i]=excl; cursor[i]=excl;
    dinv[i] = rsqrtf((float)v + 1.0f);
  }
}

__global__ void csr_fill(const int* __restrict__ src, const int* __restrict__ dst,
                         const int* __restrict__ cnt, int m_static,
                         int* __restrict__ cursor, int* __restrict__ csr){
  int m = cnt ? cnt[0] : m_static;
  int stride = gridDim.x*blockDim.x;
  for(int e = blockIdx.x*blockDim.x+threadIdx.x; e<m; e+=stride){
    int pos = atomicAdd(&cursor[dst[e]], 1);
    csr[pos] = src[e];
  }
}

// g[d,f] = dinv[d] * ( h[d,f]*dinv[d] + sum_{s in N(d)} h[s,f]*dinv[s] )
__global__ void csr_gather(const float* __restrict__ h, const float* __restrict__ dinv,
                           const int* __restrict__ rowptr, const int* __restrict__ degi,
                           const int* __restrict__ csr, float* __restrict__ g,
                           int n, int Fi, int fshift){
  long long t = (long long)blockIdx.x*blockDim.x + threadIdx.x;
  int d = (int)(t>>fshift);
  if(d>=n) return;
  int f = (int)t & (Fi-1);
  int start = rowptr[d], deg = degi[d];
  float di = dinv[d];
  float acc = h[(size_t)d*Fi+f]*di;   // self-loop term (pre di scale)
  for(int j=0;j<deg;j++){
    int s = csr[start+j];
    acc = fmaf(h[(size_t)s*Fi+f], dinv[s], acc);
  }
  g[t] = acc*di;
}

// ---------------- dense pieces ----------------

// hfull = relu(g @ W + b); thread computes one output column for 16 consecutive rows
__global__ void matmul_relu(const float* __restrict__ h, const float* __restrict__ W,
                            const float* __restrict__ b, float* __restrict__ out,
                            int n, int Fi, int Fo, int shift){
  long long t = (long long)blockIdx.x*blockDim.x + threadIdx.x;
  int c = (int)(t & (Fo-1));
  int rb = (int)(t >> shift) * 16;
  if(rb >= n) return;
  float acc[16];
  #pragma unroll
  for(int j=0;j<16;j++) acc[j]=0.f;
  int rows = n - rb; if(rows>16) rows=16;
  if(rows==16){
    for(int i=0;i<Fi;i++){
      float w = W[(size_t)i*Fo + c];
      const float* hp = h + (size_t)rb*Fi + i;
      #pragma unroll
      for(int j=0;j<16;j++) acc[j] = fmaf(hp[(size_t)j*Fi], w, acc[j]);
    }
  } else {
    for(int i=0;i<Fi;i++){
      float w = W[(size_t)i*Fo + c];
      const float* hp = h + (size_t)rb*Fi + i;
      for(int j=0;j<rows;j++) acc[j] = fmaf(hp[(size_t)j*Fi], w, acc[j]);
    }
  }
  float bc = b[c];
  for(int j=0;j<rows;j++){
    float v = acc[j] + bc;
    out[(size_t)(rb+j)*Fo + c] = v>0.f ? v : 0.f;
  }
}

// score[i] = tanh((h[i,:].p) * rsqrt(p.p)); 4 rows per block
__global__ void score2(const float* __restrict__ h, int n, int F,
                       const float* __restrict__ p, float* __restrict__ score){
  __shared__ float red[4];
  __shared__ float pninv;
  float pe = (threadIdx.x < F) ? p[threadIdx.x] : 0.f;
  float s = pe*pe;
  for(int o=32;o;o>>=1) s += __shfl_down(s,o,64);
  int lane=threadIdx.x&63, w=threadIdx.x>>6;
  if(lane==0) red[w]=s;
  __syncthreads();
  if(threadIdx.x==0) pninv = rsqrtf(red[0]+red[1]+red[2]+red[3]);
  __syncthreads();
  int wid = blockIdx.x*4 + w;
  if(wid>=n) return;
  const float* row = h + (size_t)wid*F;
  float d=0.f;
  for(int f=lane; f<F; f+=64) d = fmaf(row[f], p[f], d);
  for(int o=32;o;o>>=1) d += __shfl_down(d,o,64);
  if(lane==0) score[wid] = tanhf(d*pninv);
}

// ---------------- grid-wide two-level 16-bit top-k select ----------------
// level 1: 65536-bin histogram of high 16 bits of ordf(score), wave-aggregated
__global__ void hist_hi(const float* __restrict__ score, int n, int* __restrict__ ghist){
  int T = gridDim.x*blockDim.x;
  int lane = threadIdx.x&63;
  for(int base=0; base<n; base+=T){
    int i = base + blockIdx.x*blockDim.x + threadIdx.x;
    bool act = i<n;
    unsigned key = act ? (ordf(score[i])>>16) : 0u;
    unsigned long long eq = __ballot(act);
    #pragma unroll
    for(int bit=0;bit<16;bit++){
      unsigned long long bb = __ballot(act && ((key>>bit)&1u));
      eq &= ((key>>bit)&1u) ? bb : ~bb;
    }
    if(act){
      int lead = __ffsll(eq)-1;
      if(lane==lead) atomicAdd(&ghist[key], __popcll(eq));
    }
  }
}

// level 2: histogram of low 16 bits among elements whose high 16 match selhi
__global__ void hist_lo(const float* __restrict__ score, int n,
                        const unsigned* __restrict__ selhi, int* __restrict__ ghist){
  unsigned hi = selhi[0];
  int T = gridDim.x*blockDim.x;
  int lane = threadIdx.x&63;
  for(int base=0; base<n; base+=T){
    int i = base + blockIdx.x*blockDim.x + threadIdx.x;
    unsigned o = (i<n) ? ordf(score[i]) : 0u;
    bool act = (i<n) && ((o>>16)==hi);
    unsigned key = o & 0xFFFFu;
    unsigned long long eq = __ballot(act);
    #pragma unroll
    for(int bit=0;bit<16;bit++){
      unsigned long long bb = __ballot(act && ((key>>bit)&1u));
      eq &= ((key>>bit)&1u) ? bb : ~bb;
    }
    if(act){
      int lead = __ffsll(eq)-1;
      if(lane==lead) atomicAdd(&ghist[key], __popcll(eq));
    }
  }
}

// scan a 65536-bin histogram in DESCENDING key order; find key where cum crosses rank.
// hi_in==null: out_sel=key (level 1). hi_in set: out_sel=(hi<<16)|key (final threshold).
// out_rank = rank - (count of keys strictly greater)  [residual rank / tie quota]
__global__ void find_sel(const int* __restrict__ hist, const int* __restrict__ rank_in,
                         int rank_static, const unsigned* __restrict__ hi_in,
                         unsigned* __restrict__ out_sel, int* __restrict__ out_rank){
  __shared__ int sh[1024];
  int t = threadIdx.x;
  int rank = rank_in ? rank_in[0] : rank_static;
  int base = t*64;
  int s = 0;
  for(int u=0;u<64;u++) s += hist[65535-(base+u)];
  sh[t]=s;
  __syncthreads();
  for(int o=1;o<1024;o<<=1){
    int tv = (t>=o)?sh[t-o]:0;
    __syncthreads();
    sh[t]+=tv;
    __syncthreads();
  }
  int excl = sh[t]-s;
  if(excl < rank && rank <= excl+s){
    for(int u=0;u<64;u++){
      int c = hist[65535-(base+u)];
      if(excl + c >= rank){
        unsigned key = (unsigned)(65535-(base+u));
        out_sel[0] = hi_in ? ((hi_in[0]<<16)|key) : key;
        out_rank[0] = rank - excl;
        break;
      }
      excl += c;
    }
  }
}

// ---------------- selection compaction ----------------

__global__ void sel_blockcount(const float* __restrict__ score, int n,
                               const unsigned* __restrict__ thr,
                               int* __restrict__ blkGt, int* __restrict__ blkEq){
  int i = blockIdx.x*256 + threadIdx.x;
  unsigned vthr = thr[0];
  int gt=0, eq=0;
  if(i<n){ unsigned o=ordf(score[i]); gt = (o>vthr); eq = (o==vthr); }
  unsigned long long bg=__ballot(gt), be=__ballot(eq);
  __shared__ int sg[4], se[4];
  int lane=threadIdx.x&63, w=threadIdx.x>>6;
  if(lane==0){ sg[w]=__popcll(bg); se[w]=__popcll(be); }
  __syncthreads();
  if(threadIdx.x==0){
    int g=0,e=0;
    for(int j=0;j<4;j++){ g+=sg[j]; e+=se[j]; }
    blkGt[blockIdx.x]=g; blkEq[blockIdx.x]=e;
  }
}

// parallel exclusive scan of the two per-block count arrays (nb <= 641)
__global__ void scan_pair(int* __restrict__ blkGt, int* __restrict__ blkEq, int nb){
  __shared__ int shg[256], she[256];
  __shared__ int cg, ce;
  if(threadIdx.x==0){ cg=0; ce=0; }
  __syncthreads();
  for(int base=0;base<nb;base+=256){
    int i = base+threadIdx.x;
    int vg = (i<nb)?blkGt[i]:0;
    int ve = (i<nb)?blkEq[i]:0;
    shg[threadIdx.x]=vg; she[threadIdx.x]=ve;
    __syncthreads();
    for(int o=1;o<256;o<<=1){
      int tg = (threadIdx.x>=o)?shg[threadIdx.x-o]:0;
      int te = (threadIdx.x>=o)?she[threadIdx.x-o]:0;
      __syncthreads();
      shg[threadIdx.x]+=tg; she[threadIdx.x]+=te;
      __syncthreads();
    }
    int ig = shg[threadIdx.x], ie = she[threadIdx.x];
    int c0=cg, c1=ce;
    if(i<nb){ blkGt[i]=ig-vg+c0; blkEq[i]=ie-ve+c1; }
    __syncthreads();
    if(threadIdx.x==255){ cg=c0+ig; ce=c1+ie; }
    __syncthreads();
  }
}

__global__ void compact(const float* __restrict__ score, int n,
                        const unsigned* __restrict__ thr, const int* __restrict__ qp,
                        const int* __restrict__ blkGt, const int* __restrict__ blkEq,
                        int* __restrict__ newidx, int* __restrict__ oldidx){
  int i = blockIdx.x*256 + threadIdx.x;
  unsigned vthr = thr[0];
  int q = qp[0];
  int gt=0, eq=0;
  if(i<n){ unsigned o=ordf(score[i]); gt=(o>vthr); eq=(o==vthr); }
  unsigned long long bg=__ballot(gt), be=__ballot(eq);
  int lane=threadIdx.x&63, w=threadIdx.x>>6;
  unsigned long long mask = lane ? (~0ull >> (64-lane)) : 0ull;
  int pg = __popcll(bg & mask), pe = __popcll(be & mask);
  __shared__ int sg[4], se[4];
  if(lane==63){ sg[w]=pg+gt; se[w]=pe+eq; }
  __syncthreads();
  int wg=0,we=0;
  for(int j=0;j<w;j++){ wg+=sg[j]; we+=se[j]; }
  if(i<n){
    int gtp = blkGt[blockIdx.x] + wg + pg;
    int eqp = blkEq[blockIdx.x] + we + pe;
    int sel = gt || (eq && (eqp < q));
    if(sel){
      int pos = gtp + (eqp < q ? eqp : q);  // rank among selected, by original index
      newidx[i]=pos; oldidx[pos]=i;
    } else newidx[i]=-1;
  }
}

__global__ void gather_scale(const float* __restrict__ hfull, const float* __restrict__ score,
                             const int* __restrict__ oldidx, float* __restrict__ hout,
                             int k, int Fo, int shift){
  long long t = (long long)blockIdx.x*blockDim.x + threadIdx.x;
  int nr = (int)(t >> shift);
  if(nr >= k) return;
  int f = (int)(t & (Fo-1));
  int old = oldidx[nr];
  hout[t] = hfull[(size_t)old*Fo+f] * score[old];
}

// ---------------- scan-based edge compaction (no same-address atomics) ----------------

__global__ void edge_valid_count(const int* __restrict__ src, const int* __restrict__ dst,
                                 const int* __restrict__ cnt_in, int m_static,
                                 const int* __restrict__ newidx, int* __restrict__ bcnt){
  int m = cnt_in ? cnt_in[0] : m_static;
  int i = blockIdx.x*256 + threadIdx.x;
  int v = 0;
  if(i<m) v = (newidx[src[i]]>=0 && newidx[dst[i]]>=0);
  unsigned long long b = __ballot(v);
  __shared__ int sg[4];
  int lane=threadIdx.x&63, w=threadIdx.x>>6;
  if(lane==0) sg[w]=__popcll(b);
  __syncthreads();
  if(threadIdx.x==0) bcnt[blockIdx.x]=sg[0]+sg[1]+sg[2]+sg[3];
}

// exclusive scan of bcnt[0..nb) in place; total -> cnt_out[0]
__global__ void edge_scan(int* __restrict__ bcnt, int nb, int* __restrict__ cnt_out){
  __shared__ int sh[256];
  __shared__ int carry;
  if(threadIdx.x==0) carry=0;
  __syncthreads();
  for(int base=0;base<nb;base+=256){
    int i = base+threadIdx.x;
    int v = (i<nb) ? bcnt[i] : 0;
    sh[threadIdx.x]=v;
    __syncthreads();
    for(int o=1;o<256;o<<=1){
      int t = (threadIdx.x>=o) ? sh[threadIdx.x-o] : 0;
      __syncthreads();
      sh[threadIdx.x]+=t;
      __syncthreads();
    }
    int incl = sh[threadIdx.x];
    int c = carry;
    if(i<nb) bcnt[i] = incl - v + c;
    __syncthreads();
    if(threadIdx.x==255) carry = c + incl;
    __syncthreads();
  }
  if(threadIdx.x==0) cnt_out[0]=carry;
}

__global__ void edge_write(const int* __restrict__ src, const int* __restrict__ dst,
                           const int* __restrict__ cnt_in, int m_static,
                           const int* __restrict__ newidx, const int* __restrict__ bofs,
                           int* __restrict__ osrc, int* __restrict__ odst){
  int m = cnt_in ? cnt_in[0] : m_static;
  int i = blockIdx.x*256 + threadIdx.x;
  int v=0, ns=0, nd=0;
  if(i<m){
    ns = newidx[src[i]]; nd = newidx[dst[i]];
    v = (ns>=0 && nd>=0);
  }
  unsigned long long b = __ballot(v);
  int lane=threadIdx.x&63, w=threadIdx.x>>6;
  unsigned long long mask = lane ? (~0ull >> (64-lane)) : 0ull;
  int p = __popcll(b & mask);
  __shared__ int sg[4];
  if(lane==63) sg[w]=p+v;
  __syncthreads();
  int wofs=0;
  for(int j=0;j<w;j++) wofs+=sg[j];
  if(v){
    int pos = bofs[blockIdx.x] + wofs + p;
    osrc[pos]=ns; odst[pos]=nd;
  }
}

// ---------------- epilogue ----------------

// per-feature max & mean over final nodes; xc[0:256]=max, xc[256:512]=mean
__global__ void pool_kernel(const float* __restrict__ h, int n, float* __restrict__ xc){
  int f = blockIdx.x;
  float mx = -3.402823466e38f, sm=0.f;
  for(int r=threadIdx.x; r<n; r+=blockDim.x){
    float v = h[(size_t)r*256+f];
    mx = fmaxf(mx,v); sm += v;
  }
  __shared__ float smx[4], ssm[4];
  for(int o=32;o;o>>=1){ mx=fmaxf(mx,__shfl_down(mx,o,64)); sm+=__shfl_down(sm,o,64); }
  int lane=threadIdx.x&63, w=threadIdx.x>>6;
  if(lane==0){ smx[w]=mx; ssm[w]=sm; }
  __syncthreads();
  if(threadIdx.x==0){
    for(int j=1;j<4;j++){ mx=fmaxf(mx,smx[j]); sm+=ssm[j]; }
    xc[f]=mx; xc[256+f]=sm/(float)n;
  }
}

__global__ void fc_kernel(const float* __restrict__ xc, const float* __restrict__ fcw,
                          const float* __restrict__ fcb, const float* __restrict__ fc2w,
                          const float* __restrict__ fc2b, float* __restrict__ out){
  __shared__ float x[512];
  for(int i=threadIdx.x;i<512;i+=256) x[i]=xc[i];
  __syncthreads();
  int j=threadIdx.x;
  float a=fcb[j];
  for(int i=0;i<512;i++) a = fmaf(x[i], fcw[(size_t)j*512+i], a);
  a = a>0.f ? a : 0.f;
  float v = a*fc2w[j];
  for(int o=32;o;o>>=1) v += __shfl_down(v,o,64);
  __shared__ float sv[4];
  int lane=threadIdx.x&63, w=threadIdx.x>>6;
  if(lane==0) sv[w]=v;
  __syncthreads();
  if(threadIdx.x==0) out[0]=sv[0]+sv[1]+sv[2]+sv[3]+fc2b[0];
}

extern "C" void kernel_launch(void* const* d_in, const int* in_sizes, int n_in,
                              void* d_out, int out_size, void* d_ws, size_t ws_size,
                              hipStream_t stream) {
  const float* x   = (const float*)d_in[0];
  const int*   ei  = (const int*)d_in[1];
  const float* Wm[4] = {(const float*)d_in[2],(const float*)d_in[5],(const float*)d_in[8],(const float*)d_in[11]};
  const float* bv[4] = {(const float*)d_in[3],(const float*)d_in[6],(const float*)d_in[9],(const float*)d_in[12]};
  const float* pv[4] = {(const float*)d_in[4],(const float*)d_in[7],(const float*)d_in[10],(const float*)d_in[13]};
  const float* fcw  = (const float*)d_in[14];
  const float* fcb  = (const float*)d_in[15];
  const float* fc2w = (const float*)d_in[16];
  const float* fc2b = (const float*)d_in[17];

  char* base = (char*)d_ws; size_t off=0;
  auto alloc = [&](size_t bytes)->void*{
    void* p = base + off; off += (bytes + 511) & ~(size_t)511; return p;
  };
  int*   es1    = (int*)  alloc((size_t)NE*4);
  int*   ed1    = (int*)  alloc((size_t)NE*4);
  int*   es2    = (int*)  alloc((size_t)NE*4);
  int*   ed2    = (int*)  alloc((size_t)NE*4);
  int*   csr    = (int*)  alloc((size_t)NE*4);
  int*   degi   = (int*)  alloc((size_t)NV*4);
  int*   rowptr = (int*)  alloc((size_t)NV*4);
  int*   cursor = (int*)  alloc((size_t)NV*4);
  float* dinv   = (float*)alloc((size_t)NV*4);
  float* score  = (float*)alloc((size_t)NV*4);
  int*   newidx = (int*)  alloc((size_t)NV*4);
  int*   oldidx = (int*)  alloc((size_t)NV*4);
  float* g      = (float*)alloc((size_t)2621568*4);
  float* hfull  = (float*)alloc((size_t)5243136*4);
  float* hbuf   = (float*)alloc((size_t)2621696*4);
  int*   ghist  = (int*)  alloc((size_t)131072*4);   // two 65536-bin histograms
  int*   bsum   = (int*)  alloc(4096);
  int*   ebcnt  = (int*)  alloc((size_t)NBE*4+512);
  int*   cnt    = (int*)  alloc(64);
  unsigned* thr = (unsigned*)alloc(64);
  int*   qv     = (int*)  alloc(64);
  unsigned* selhi = (unsigned*)alloc(64);
  int*   rank2  = (int*)  alloc(64);
  int*   blkGt  = (int*)  alloc(4096);
  int*   blkEq  = (int*)  alloc(4096);
  float* xc     = (float*)alloc(2048);
  if (off > ws_size) return;

  const int ns[5]   = {163842, 81921, 40961, 20481, 10241};
  const int dims[5] = {4, 32, 64, 128, 256};
  const int foshf[4]= {5, 6, 7, 8};     // log2(Fo)
  const int fishf[4]= {2, 5, 6, 7};     // log2(Fi)

  const int* curS[4] = {ei,      es1, es2, es1};
  const int* curD[4] = {ei + NE, ed1, ed2, ed1};
  int*       outS[3] = {es1, es2, es1};
  int*       outD[3] = {ed1, ed2, ed1};

  const float* hin = x;
  for(int l=0;l<4;l++){
    int n=ns[l], k=ns[l+1], Fi=dims[l], Fo=dims[l+1];
    const int* cin = (l==0) ? nullptr : (cnt + (l-1));
    int nb = (n+255)/256;
    // ---- CSR build ----
    hipMemsetAsync(degi, 0, (size_t)n*4, stream);
    unsigned egrid = (l==0) ? 2048 : 1024;
    deg_count<<<egrid,256,0,stream>>>(curD[l], cin, NE, degi);
    block_sums<<<nb,256,0,stream>>>(degi, n, bsum);
    scan_bsums<<<1,256,0,stream>>>(bsum, nb);
    scan_local<<<nb,256,0,stream>>>(degi, bsum, n, rowptr, cursor, dinv);
    csr_fill<<<egrid,256,0,stream>>>(curS[l], curD[l], cin, NE, cursor, csr);
    // ---- aggregation (gather, no atomics) ----
    long long nf = (long long)n*Fi;
    csr_gather<<<(unsigned)((nf+255)/256),256,0,stream>>>(hin, dinv, rowptr, degi, csr, g, n, Fi, fishf[l]);
    // ---- dense: hfull = relu(g@W + b) ----
    long long rbc = (n+15)/16;
    matmul_relu<<<(unsigned)((rbc*Fo+255)/256),256,0,stream>>>(g, Wm[l], bv[l], hfull, n, Fi, Fo, foshf[l]);
    // ---- top-k selection (grid-wide two-level 16-bit select) ----
    score2<<<(n+3)/4,256,0,stream>>>(hfull, n, Fo, pv[l], score);
    hipMemsetAsync(ghist, 0, (size_t)131072*4, stream);
    hist_hi<<<256,256,0,stream>>>(score, n, ghist);
    find_sel<<<1,1024,0,stream>>>(ghist, nullptr, k, nullptr, selhi, rank2);
    hist_lo<<<256,256,0,stream>>>(score, n, selhi, ghist+65536);
    find_sel<<<1,1024,0,stream>>>(ghist+65536, rank2, 0, selhi, thr, qv);
    // ---- compaction ----
    sel_blockcount<<<nb,256,0,stream>>>(score, n, thr, blkGt, blkEq);
    scan_pair<<<1,256,0,stream>>>(blkGt, blkEq, nb);
    compact<<<nb,256,0,stream>>>(score, n, thr, qv, blkGt, blkEq, newidx, oldidx);
    gather_scale<<<(unsigned)((((long long)k*Fo)+255)/256),256,0,stream>>>(hfull, score, oldidx, hbuf, k, Fo, foshf[l]);
    // ---- edge compaction for next layer (deterministic scan, no hot atomics) ----
    if(l<3){
      edge_valid_count<<<NBE,256,0,stream>>>(curS[l], curD[l], cin, NE, newidx, ebcnt);
      edge_scan<<<1,256,0,stream>>>(ebcnt, NBE, cnt + l);
      edge_write<<<NBE,256,0,stream>>>(curS[l], curD[l], cin, NE, newidx, ebcnt, outS[l], outD[l]);
    }
    hin = hbuf;
  }

  pool_kernel<<<256,256,0,stream>>>(hbuf, ns[4], xc);
  fc_kernel<<<1,256,0,stream>>>(xc, fcw, fcb, fc2w, fc2b, (float*)d_out);
}

// Round 6
// 850.789 us; speedup vs baseline: 1.7729x; 1.0905x over previous
//
#include <hip/hip_runtime.h>
#include <math.h>

#define NV 163842
#define NE 983052
#define NBE 3841   // ceil(NE/256)

// order-preserving float->uint transform (descending top-k: larger value -> larger key)
static __device__ __forceinline__ unsigned ordf(float f){
  unsigned u = __float_as_uint(f);
  return (u & 0x80000000u) ? ~u : (u | 0x80000000u);
}

// ---------------- CSR build ----------------

__global__ void deg_count(const int* __restrict__ dst, const int* __restrict__ cnt,
                          int m_static, int* __restrict__ degi){
  int m = cnt ? cnt[0] : m_static;
  int stride = gridDim.x*blockDim.x;
  for(int e = blockIdx.x*blockDim.x+threadIdx.x; e<m; e+=stride)
    atomicAdd(&degi[dst[e]], 1);
}

// per-256-block sums of degi
__global__ void block_sums(const int* __restrict__ degi, int n, int* __restrict__ bsum){
  int i = blockIdx.x*256 + threadIdx.x;
  int v = (i<n) ? degi[i] : 0;
  for(int o=32;o;o>>=1) v += __shfl_down(v,o,64);
  __shared__ int sg[4];
  int lane=threadIdx.x&63, w=threadIdx.x>>6;
  if(lane==0) sg[w]=v;
  __syncthreads();
  if(threadIdx.x==0) bsum[blockIdx.x]=sg[0]+sg[1]+sg[2]+sg[3];
}

// in-place exclusive scan of bsum[0..nb), single block, chunked LDS scan
__global__ void scan_bsums(int* __restrict__ bsum, int nb){
  __shared__ int sh[256];
  __shared__ int carry;
  if(threadIdx.x==0) carry=0;
  __syncthreads();
  for(int base=0;base<nb;base+=256){
    int i = base+threadIdx.x;
    int v = (i<nb) ? bsum[i] : 0;
    sh[threadIdx.x]=v;
    __syncthreads();
    for(int o=1;o<256;o<<=1){
      int t = (threadIdx.x>=o) ? sh[threadIdx.x-o] : 0;
      __syncthreads();
      sh[threadIdx.x]+=t;
      __syncthreads();
    }
    int incl = sh[threadIdx.x];
    int c = carry;
    if(i<nb) bsum[i] = incl - v + c;
    __syncthreads();
    if(threadIdx.x==255) carry = c + incl;
    __syncthreads();
  }
}

// rowptr[i] = exclusive scan of degi (+ block offset); also cursor copy and dinv
__global__ void scan_local(const int* __restrict__ degi, const int* __restrict__ bofs,
                           int n, int* __restrict__ rowptr, int* __restrict__ cursor,
                           float* __restrict__ dinv){
  __shared__ int sh[256];
  int i = blockIdx.x*256 + threadIdx.x;
  int v = (i<n) ? degi[i] : 0;
  sh[threadIdx.x]=v;
  __syncthreads();
  for(int o=1;o<256;o<<=1){
    int t = (threadIdx.x>=o) ? sh[threadIdx.x-o] : 0;
    __syncthreads();
    sh[threadIdx.x]+=t;
    __syncthreads();
  }
  if(i<n){
    int excl = sh[threadIdx.x] - v + bofs[blockIdx.x];
    rowptr[i]=excl; cursor[i]=excl;
    dinv[i] = rsqrtf((float)v + 1.0f);
  }
}

__global__ void csr_fill(const int* __restrict__ src, const int* __restrict__ dst,
                         const int* __restrict__ cnt, int m_static,
                         int* __restrict__ cursor, int* __restrict__ csr){
  int m = cnt ? cnt[0] : m_static;
  int stride = gridDim.x*blockDim.x;
  for(int e = blockIdx.x*blockDim.x+threadIdx.x; e<m; e+=stride){
    int pos = atomicAdd(&cursor[dst[e]], 1);
    csr[pos] = src[e];
  }
}

// g[d, q..q+3] = dinv[d]*( h[d]*dinv[d] + sum_{s in N(d)} h[s]*dinv[s] ), float4 per thread
__global__ void csr_gather4(const float* __restrict__ h, const float* __restrict__ dinv,
                            const int* __restrict__ rowptr, const int* __restrict__ degi,
                            const int* __restrict__ csr, float* __restrict__ g,
                            int n, int Fi, int qshift){
  long long t = (long long)blockIdx.x*blockDim.x + threadIdx.x;
  int d = (int)(t >> qshift);
  if(d>=n) return;
  int q = ((int)t & ((1<<qshift)-1)) << 2;
  int start = rowptr[d], deg = degi[d];
  float di = dinv[d];
  float4 hv = *(const float4*)(h + (size_t)d*Fi + q);
  float4 acc = make_float4(hv.x*di, hv.y*di, hv.z*di, hv.w*di);
  for(int j=0;j<deg;j++){
    int s = csr[start+j];
    float ds = dinv[s];
    float4 hs = *(const float4*)(h + (size_t)s*Fi + q);
    acc.x = fmaf(hs.x, ds, acc.x);
    acc.y = fmaf(hs.y, ds, acc.y);
    acc.z = fmaf(hs.z, ds, acc.z);
    acc.w = fmaf(hs.w, ds, acc.w);
  }
  *(float4*)(g + (size_t)d*Fi + q) = make_float4(acc.x*di, acc.y*di, acc.z*di, acc.w*di);
}

// ---------------- fused dense: hfull = relu(g@W+b); score = tanh(hfull.p/||p||) ----------------
// block = 256 threads = G row-groups (G=256/Fo) x Fo columns; 16 rows per group.
// K-loop unrolled x4 with float4 h loads. Score reduced via shfl + LDS tree (deterministic).
__global__ void matmul_relu_score(const float* __restrict__ h, const float* __restrict__ W,
                                  const float* __restrict__ b, const float* __restrict__ p,
                                  float* __restrict__ out, float* __restrict__ score,
                                  int n, int Fi, int Fo, int foshf){
  __shared__ float sp[8][4][16];
  __shared__ float pn_sh;
  int tid = threadIdx.x;
  int c  = tid & (Fo-1);
  int rg = tid >> foshf;
  int G  = 256 >> foshf;
  int rb = (blockIdx.x*G + rg)*16;
  // ||p||^-1 by wave 0
  if(tid < 64){
    float s=0.f;
    for(int f=tid; f<Fo; f+=64) s += p[f]*p[f];
    for(int o=32;o;o>>=1) s += __shfl_down(s,o,64);
    if(tid==0) pn_sh = rsqrtf(s);
  }
  float acc[16];
  #pragma unroll
  for(int j=0;j<16;j++) acc[j]=0.f;
  int rows = n - rb; if(rows>16) rows=16;
  if(rows==16){
    for(int i=0;i<Fi;i+=4){
      float w0=W[(size_t)i*Fo+c], w1=W[(size_t)(i+1)*Fo+c];
      float w2=W[(size_t)(i+2)*Fo+c], w3=W[(size_t)(i+3)*Fo+c];
      const float* hp = h + (size_t)rb*Fi + i;
      #pragma unroll
      for(int j=0;j<16;j++){
        float4 hv = *(const float4*)(hp + (size_t)j*Fi);
        acc[j] = fmaf(hv.x,w0, fmaf(hv.y,w1, fmaf(hv.z,w2, fmaf(hv.w,w3, acc[j]))));
      }
    }
  } else if(rows > 0){
    for(int i=0;i<Fi;i+=4){
      float w0=W[(size_t)i*Fo+c], w1=W[(size_t)(i+1)*Fo+c];
      float w2=W[(size_t)(i+2)*Fo+c], w3=W[(size_t)(i+3)*Fo+c];
      const float* hp = h + (size_t)rb*Fi + i;
      for(int j=0;j<rows;j++){
        float4 hv = *(const float4*)(hp + (size_t)j*Fi);
        acc[j] = fmaf(hv.x,w0, fmaf(hv.y,w1, fmaf(hv.z,w2, fmaf(hv.w,w3, acc[j]))));
      }
    }
  }
  float bc = b[c];
  float pc = p[c];
  int width = (Fo < 64) ? Fo : 64;
  #pragma unroll
  for(int j=0;j<16;j++){
    float v = acc[j] + bc;
    v = v>0.f ? v : 0.f;
    if(j<rows) out[(size_t)(rb+j)*Fo + c] = v;
    // score partial: reduce v*p[c] over the row's Fo columns
    float sc = v*pc;
    for(int o=width>>1; o; o>>=1) sc += __shfl_down(sc, o, width);
    if((c & 63)==0) sp[rg][c>>6][j] = sc;
  }
  __syncthreads();
  if(tid < (G<<4)){
    int g2 = tid >> 4, j2 = tid & 15;
    int row = (blockIdx.x*G + g2)*16 + j2;
    if(row < n){
      int P = (Fo >= 64) ? (Fo>>6) : 1;
      float s2 = sp[g2][0][j2];
      for(int pp=1; pp<P; pp++) s2 += sp[g2][pp][j2];
      score[row] = tanhf(s2 * pn_sh);
    }
  }
}

// ---------------- grid-wide two-level 16-bit top-k select ----------------
__global__ void hist_hi(const float* __restrict__ score, int n, int* __restrict__ ghist){
  int T = gridDim.x*blockDim.x;
  int lane = threadIdx.x&63;
  for(int base=0; base<n; base+=T){
    int i = base + blockIdx.x*blockDim.x + threadIdx.x;
    bool act = i<n;
    unsigned key = act ? (ordf(score[i])>>16) : 0u;
    unsigned long long eq = __ballot(act);
    #pragma unroll
    for(int bit=0;bit<16;bit++){
      unsigned long long bb = __ballot(act && ((key>>bit)&1u));
      eq &= ((key>>bit)&1u) ? bb : ~bb;
    }
    if(act){
      int lead = __ffsll(eq)-1;
      if(lane==lead) atomicAdd(&ghist[key], __popcll(eq));
    }
  }
}

__global__ void hist_lo(const float* __restrict__ score, int n,
                        const unsigned* __restrict__ selhi, int* __restrict__ ghist){
  unsigned hi = selhi[0];
  int T = gridDim.x*blockDim.x;
  int lane = threadIdx.x&63;
  for(int base=0; base<n; base+=T){
    int i = base + blockIdx.x*blockDim.x + threadIdx.x;
    unsigned o = (i<n) ? ordf(score[i]) : 0u;
    bool act = (i<n) && ((o>>16)==hi);
    unsigned key = o & 0xFFFFu;
    unsigned long long eq = __ballot(act);
    #pragma unroll
    for(int bit=0;bit<16;bit++){
      unsigned long long bb = __ballot(act && ((key>>bit)&1u));
      eq &= ((key>>bit)&1u) ? bb : ~bb;
    }
    if(act){
      int lead = __ffsll(eq)-1;
      if(lane==lead) atomicAdd(&ghist[key], __popcll(eq));
    }
  }
}

// scan 65536-bin histogram in DESCENDING key order; find crossing of rank
__global__ void find_sel(const int* __restrict__ hist, const int* __restrict__ rank_in,
                         int rank_static, const unsigned* __restrict__ hi_in,
                         unsigned* __restrict__ out_sel, int* __restrict__ out_rank){
  __shared__ int sh[1024];
  int t = threadIdx.x;
  int rank = rank_in ? rank_in[0] : rank_static;
  int base = t*64;
  int s = 0;
  for(int u=0;u<64;u++) s += hist[65535-(base+u)];
  sh[t]=s;
  __syncthreads();
  for(int o=1;o<1024;o<<=1){
    int tv = (t>=o)?sh[t-o]:0;
    __syncthreads();
    sh[t]+=tv;
    __syncthreads();
  }
  int excl = sh[t]-s;
  if(excl < rank && rank <= excl+s){
    for(int u=0;u<64;u++){
      int c = hist[65535-(base+u)];
      if(excl + c >= rank){
        unsigned key = (unsigned)(65535-(base+u));
        out_sel[0] = hi_in ? ((hi_in[0]<<16)|key) : key;
        out_rank[0] = rank - excl;
        break;
      }
      excl += c;
    }
  }
}

// ---------------- selection compaction ----------------

__global__ void sel_blockcount(const float* __restrict__ score, int n,
                               const unsigned* __restrict__ thr,
                               int* __restrict__ blkGt, int* __restrict__ blkEq){
  int i = blockIdx.x*256 + threadIdx.x;
  unsigned vthr = thr[0];
  int gt=0, eq=0;
  if(i<n){ unsigned o=ordf(score[i]); gt = (o>vthr); eq = (o==vthr); }
  unsigned long long bg=__ballot(gt), be=__ballot(eq);
  __shared__ int sg[4], se[4];
  int lane=threadIdx.x&63, w=threadIdx.x>>6;
  if(lane==0){ sg[w]=__popcll(bg); se[w]=__popcll(be); }
  __syncthreads();
  if(threadIdx.x==0){
    int g=0,e=0;
    for(int j=0;j<4;j++){ g+=sg[j]; e+=se[j]; }
    blkGt[blockIdx.x]=g; blkEq[blockIdx.x]=e;
  }
}

__global__ void scan_pair(int* __restrict__ blkGt, int* __restrict__ blkEq, int nb){
  __shared__ int shg[256], she[256];
  __shared__ int cg, ce;
  if(threadIdx.x==0){ cg=0; ce=0; }
  __syncthreads();
  for(int base=0;base<nb;base+=256){
    int i = base+threadIdx.x;
    int vg = (i<nb)?blkGt[i]:0;
    int ve = (i<nb)?blkEq[i]:0;
    shg[threadIdx.x]=vg; she[threadIdx.x]=ve;
    __syncthreads();
    for(int o=1;o<256;o<<=1){
      int tg = (threadIdx.x>=o)?shg[threadIdx.x-o]:0;
      int te = (threadIdx.x>=o)?she[threadIdx.x-o]:0;
      __syncthreads();
      shg[threadIdx.x]+=tg; she[threadIdx.x]+=te;
      __syncthreads();
    }
    int ig = shg[threadIdx.x], ie = she[threadIdx.x];
    int c0=cg, c1=ce;
    if(i<nb){ blkGt[i]=ig-vg+c0; blkEq[i]=ie-ve+c1; }
    __syncthreads();
    if(threadIdx.x==255){ cg=c0+ig; ce=c1+ie; }
    __syncthreads();
  }
}

__global__ void compact(const float* __restrict__ score, int n,
                        const unsigned* __restrict__ thr, const int* __restrict__ qp,
                        const int* __restrict__ blkGt, const int* __restrict__ blkEq,
                        int* __restrict__ newidx, int* __restrict__ oldidx){
  int i = blockIdx.x*256 + threadIdx.x;
  unsigned vthr = thr[0];
  int q = qp[0];
  int gt=0, eq=0;
  if(i<n){ unsigned o=ordf(score[i]); gt=(o>vthr); eq=(o==vthr); }
  unsigned long long bg=__ballot(gt), be=__ballot(eq);
  int lane=threadIdx.x&63, w=threadIdx.x>>6;
  unsigned long long mask = lane ? (~0ull >> (64-lane)) : 0ull;
  int pg = __popcll(bg & mask), pe = __popcll(be & mask);
  __shared__ int sg[4], se[4];
  if(lane==63){ sg[w]=pg+gt; se[w]=pe+eq; }
  __syncthreads();
  int wg=0,we=0;
  for(int j=0;j<w;j++){ wg+=sg[j]; we+=se[j]; }
  if(i<n){
    int gtp = blkGt[blockIdx.x] + wg + pg;
    int eqp = blkEq[blockIdx.x] + we + pe;
    int sel = gt || (eq && (eqp < q));
    if(sel){
      int pos = gtp + (eqp < q ? eqp : q);  // rank among selected, by original index
      newidx[i]=pos; oldidx[pos]=i;
    } else newidx[i]=-1;
  }
}

// hout[nr, q..q+3] = hfull[old, q..q+3] * score[old], float4 per thread
__global__ void gather_scale4(const float* __restrict__ hfull, const float* __restrict__ score,
                              const int* __restrict__ oldidx, float* __restrict__ hout,
                              int k, int Fo, int foshf){
  long long t = (long long)blockIdx.x*blockDim.x + threadIdx.x;
  int nr = (int)(t >> (foshf-2));
  if(nr >= k) return;
  int q = ((int)t & ((Fo>>2)-1)) << 2;
  int old = oldidx[nr];
  float s = score[old];
  float4 v = *(const float4*)(hfull + (size_t)old*Fo + q);
  *(float4*)(hout + (size_t)nr*Fo + q) = make_float4(v.x*s, v.y*s, v.z*s, v.w*s);
}

// ---------------- scan-based edge compaction ----------------

__global__ void edge_valid_count(const int* __restrict__ src, const int* __restrict__ dst,
                                 const int* __restrict__ cnt_in, int m_static,
                                 const int* __restrict__ newidx, int* __restrict__ bcnt){
  int m = cnt_in ? cnt_in[0] : m_static;
  int i = blockIdx.x*256 + threadIdx.x;
  int v = 0;
  if(i<m) v = (newidx[src[i]]>=0 && newidx[dst[i]]>=0);
  unsigned long long b = __ballot(v);
  __shared__ int sg[4];
  int lane=threadIdx.x&63, w=threadIdx.x>>6;
  if(lane==0) sg[w]=__popcll(b);
  __syncthreads();
  if(threadIdx.x==0) bcnt[blockIdx.x]=sg[0]+sg[1]+sg[2]+sg[3];
}

__global__ void edge_scan(int* __restrict__ bcnt, int nb, int* __restrict__ cnt_out){
  __shared__ int sh[256];
  __shared__ int carry;
  if(threadIdx.x==0) carry=0;
  __syncthreads();
  for(int base=0;base<nb;base+=256){
    int i = base+threadIdx.x;
    int v = (i<nb) ? bcnt[i] : 0;
    sh[threadIdx.x]=v;
    __syncthreads();
    for(int o=1;o<256;o<<=1){
      int t = (threadIdx.x>=o) ? sh[threadIdx.x-o] : 0;
      __syncthreads();
      sh[threadIdx.x]+=t;
      __syncthreads();
    }
    int incl = sh[threadIdx.x];
    int c = carry;
    if(i<nb) bcnt[i] = incl - v + c;
    __syncthreads();
    if(threadIdx.x==255) carry = c + incl;
    __syncthreads();
  }
  if(threadIdx.x==0) cnt_out[0]=carry;
}

__global__ void edge_write(const int* __restrict__ src, const int* __restrict__ dst,
                           const int* __restrict__ cnt_in, int m_static,
                           const int* __restrict__ newidx, const int* __restrict__ bofs,
                           int* __restrict__ osrc, int* __restrict__ odst){
  int m = cnt_in ? cnt_in[0] : m_static;
  int i = blockIdx.x*256 + threadIdx.x;
  int v=0, ns=0, nd=0;
  if(i<m){
    ns = newidx[src[i]]; nd = newidx[dst[i]];
    v = (ns>=0 && nd>=0);
  }
  unsigned long long b = __ballot(v);
  int lane=threadIdx.x&63, w=threadIdx.x>>6;
  unsigned long long mask = lane ? (~0ull >> (64-lane)) : 0ull;
  int p = __popcll(b & mask);
  __shared__ int sg[4];
  if(lane==63) sg[w]=p+v;
  __syncthreads();
  int wofs=0;
  for(int j=0;j<w;j++) wofs+=sg[j];
  if(v){
    int pos = bofs[blockIdx.x] + wofs + p;
    osrc[pos]=ns; odst[pos]=nd;
  }
}

// ---------------- epilogue ----------------

__global__ void pool_kernel(const float* __restrict__ h, int n, float* __restrict__ xc){
  int f = blockIdx.x;
  float mx = -3.402823466e38f, sm=0.f;
  for(int r=threadIdx.x; r<n; r+=blockDim.x){
    float v = h[(size_t)r*256+f];
    mx = fmaxf(mx,v); sm += v;
  }
  __shared__ float smx[4], ssm[4];
  for(int o=32;o;o>>=1){ mx=fmaxf(mx,__shfl_down(mx,o,64)); sm+=__shfl_down(sm,o,64); }
  int lane=threadIdx.x&63, w=threadIdx.x>>6;
  if(lane==0){ smx[w]=mx; ssm[w]=sm; }
  __syncthreads();
  if(threadIdx.x==0){
    for(int j=1;j<4;j++){ mx=fmaxf(mx,smx[j]); sm+=ssm[j]; }
    xc[f]=mx; xc[256+f]=sm/(float)n;
  }
}

__global__ void fc_kernel(const float* __restrict__ xc, const float* __restrict__ fcw,
                          const float* __restrict__ fcb, const float* __restrict__ fc2w,
                          const float* __restrict__ fc2b, float* __restrict__ out){
  __shared__ float x[512];
  for(int i=threadIdx.x;i<512;i+=256) x[i]=xc[i];
  __syncthreads();
  int j=threadIdx.x;
  float a=fcb[j];
  for(int i=0;i<512;i++) a = fmaf(x[i], fcw[(size_t)j*512+i], a);
  a = a>0.f ? a : 0.f;
  float v = a*fc2w[j];
  for(int o=32;o;o>>=1) v += __shfl_down(v,o,64);
  __shared__ float sv[4];
  int lane=threadIdx.x&63, w=threadIdx.x>>6;
  if(lane==0) sv[w]=v;
  __syncthreads();
  if(threadIdx.x==0) out[0]=sv[0]+sv[1]+sv[2]+sv[3]+fc2b[0];
}

extern "C" void kernel_launch(void* const* d_in, const int* in_sizes, int n_in,
                              void* d_out, int out_size, void* d_ws, size_t ws_size,
                              hipStream_t stream) {
  const float* x   = (const float*)d_in[0];
  const int*   ei  = (const int*)d_in[1];
  const float* Wm[4] = {(const float*)d_in[2],(const float*)d_in[5],(const float*)d_in[8],(const float*)d_in[11]};
  const float* bv[4] = {(const float*)d_in[3],(const float*)d_in[6],(const float*)d_in[9],(const float*)d_in[12]};
  const float* pv[4] = {(const float*)d_in[4],(const float*)d_in[7],(const float*)d_in[10],(const float*)d_in[13]};
  const float* fcw  = (const float*)d_in[14];
  const float* fcb  = (const float*)d_in[15];
  const float* fc2w = (const float*)d_in[16];
  const float* fc2b = (const float*)d_in[17];

  char* base = (char*)d_ws; size_t off=0;
  auto alloc = [&](size_t bytes)->void*{
    void* p = base + off; off += (bytes + 511) & ~(size_t)511; return p;
  };
  int*   es1    = (int*)  alloc((size_t)NE*4);
  int*   ed1    = (int*)  alloc((size_t)NE*4);
  int*   es2    = (int*)  alloc((size_t)NE*4);
  int*   ed2    = (int*)  alloc((size_t)NE*4);
  int*   csr    = (int*)  alloc((size_t)NE*4);
  int*   degi   = (int*)  alloc((size_t)NV*4);
  int*   rowptr = (int*)  alloc((size_t)NV*4);
  int*   cursor = (int*)  alloc((size_t)NV*4);
  float* dinv   = (float*)alloc((size_t)NV*4);
  float* score  = (float*)alloc((size_t)NV*4);
  int*   newidx = (int*)  alloc((size_t)NV*4);
  int*   oldidx = (int*)  alloc((size_t)NV*4);
  float* g      = (float*)alloc((size_t)2621568*4);
  float* hfull  = (float*)alloc((size_t)5243136*4);
  float* hbuf   = (float*)alloc((size_t)2621696*4);
  int*   ghist  = (int*)  alloc((size_t)131072*4);
  int*   bsum   = (int*)  alloc(4096);
  int*   ebcnt  = (int*)  alloc((size_t)NBE*4+512);
  int*   cnt    = (int*)  alloc(64);
  unsigned* thr = (unsigned*)alloc(64);
  int*   qv     = (int*)  alloc(64);
  unsigned* selhi = (unsigned*)alloc(64);
  int*   rank2  = (int*)  alloc(64);
  int*   blkGt  = (int*)  alloc(4096);
  int*   blkEq  = (int*)  alloc(4096);
  float* xc     = (float*)alloc(2048);
  if (off > ws_size) return;

  const int ns[5]   = {163842, 81921, 40961, 20481, 10241};
  const int dims[5] = {4, 32, 64, 128, 256};
  const int foshf[4]= {5, 6, 7, 8};     // log2(Fo)
  const int qshf[4] = {0, 3, 4, 5};     // log2(Fi/4)

  const int* curS[4] = {ei,      es1, es2, es1};
  const int* curD[4] = {ei + NE, ed1, ed2, ed1};
  int*       outS[3] = {es1, es2, es1};
  int*       outD[3] = {ed1, ed2, ed1};

  const float* hin = x;
  for(int l=0;l<4;l++){
    int n=ns[l], k=ns[l+1], Fi=dims[l], Fo=dims[l+1];
    const int* cin = (l==0) ? nullptr : (cnt + (l-1));
    int nb = (n+255)/256;
    // ---- CSR build ----
    hipMemsetAsync(degi, 0, (size_t)n*4, stream);
    unsigned egrid = (l==0) ? 2048 : 1024;
    deg_count<<<egrid,256,0,stream>>>(curD[l], cin, NE, degi);
    block_sums<<<nb,256,0,stream>>>(degi, n, bsum);
    scan_bsums<<<1,256,0,stream>>>(bsum, nb);
    scan_local<<<nb,256,0,stream>>>(degi, bsum, n, rowptr, cursor, dinv);
    csr_fill<<<egrid,256,0,stream>>>(curS[l], curD[l], cin, NE, cursor, csr);
    // ---- aggregation (gather, float4, no atomics) ----
    long long nq = (long long)n << qshf[l];
    csr_gather4<<<(unsigned)((nq+255)/256),256,0,stream>>>(hin, dinv, rowptr, degi, csr, g, n, Fi, qshf[l]);
    // ---- fused dense + score ----
    int G = 256 >> foshf[l];
    unsigned mgrid = (unsigned)((n + G*16 - 1) / (G*16));
    matmul_relu_score<<<mgrid,256,0,stream>>>(g, Wm[l], bv[l], pv[l], hfull, score, n, Fi, Fo, foshf[l]);
    // ---- top-k selection (grid-wide two-level 16-bit select) ----
    hipMemsetAsync(ghist, 0, (size_t)131072*4, stream);
    hist_hi<<<256,256,0,stream>>>(score, n, ghist);
    find_sel<<<1,1024,0,stream>>>(ghist, nullptr, k, nullptr, selhi, rank2);
    hist_lo<<<256,256,0,stream>>>(score, n, selhi, ghist+65536);
    find_sel<<<1,1024,0,stream>>>(ghist+65536, rank2, 0, selhi, thr, qv);
    // ---- compaction ----
    sel_blockcount<<<nb,256,0,stream>>>(score, n, thr, blkGt, blkEq);
    scan_pair<<<1,256,0,stream>>>(blkGt, blkEq, nb);
    compact<<<nb,256,0,stream>>>(score, n, thr, qv, blkGt, blkEq, newidx, oldidx);
    long long kq = (long long)k << (foshf[l]-2);
    gather_scale4<<<(unsigned)((kq+255)/256),256,0,stream>>>(hfull, score, oldidx, hbuf, k, Fo, foshf[l]);
    // ---- edge compaction for next layer ----
    if(l<3){
      edge_valid_count<<<NBE,256,0,stream>>>(curS[l], curD[l], cin, NE, newidx, ebcnt);
      edge_scan<<<1,256,0,stream>>>(ebcnt, NBE, cnt + l);
      edge_write<<<NBE,256,0,stream>>>(curS[l], curD[l], cin, NE, newidx, ebcnt, outS[l], outD[l]);
    }
    hin = hbuf;
  }

  pool_kernel<<<256,256,0,stream>>>(hbuf, ns[4], xc);
  fc_kernel<<<1,256,0,stream>>>(xc, fcw, fcb, fc2w, fc2b, (float*)d_out);
}

// Round 7
// 815.836 us; speedup vs baseline: 1.8488x; 1.0428x over previous
//
#include <hip/hip_runtime.h>
#include <math.h>

#define NV 163842
#define NE 983052
#define NBE 3841   // ceil(NE/256)

// order-preserving float->uint transform (descending top-k: larger value -> larger key)
static __device__ __forceinline__ unsigned ordf(float f){
  unsigned u = __float_as_uint(f);
  return (u & 0x80000000u) ? ~u : (u | 0x80000000u);
}

// ---------------- CSR build ----------------

__global__ void deg_count(const int* __restrict__ dst, const int* __restrict__ cnt,
                          int m_static, int* __restrict__ degi){
  int m = cnt ? cnt[0] : m_static;
  int stride = gridDim.x*blockDim.x;
  for(int e = blockIdx.x*blockDim.x+threadIdx.x; e<m; e+=stride)
    atomicAdd(&degi[dst[e]], 1);
}

// per-256-block sums of degi
__global__ void block_sums(const int* __restrict__ degi, int n, int* __restrict__ bsum){
  int i = blockIdx.x*256 + threadIdx.x;
  int v = (i<n) ? degi[i] : 0;
  for(int o=32;o;o>>=1) v += __shfl_down(v,o,64);
  __shared__ int sg[4];
  int lane=threadIdx.x&63, w=threadIdx.x>>6;
  if(lane==0) sg[w]=v;
  __syncthreads();
  if(threadIdx.x==0) bsum[blockIdx.x]=sg[0]+sg[1]+sg[2]+sg[3];
}

// in-place exclusive scan of bsum[0..nb), single block, chunked LDS scan
__global__ void scan_bsums(int* __restrict__ bsum, int nb){
  __shared__ int sh[256];
  __shared__ int carry;
  if(threadIdx.x==0) carry=0;
  __syncthreads();
  for(int base=0;base<nb;base+=256){
    int i = base+threadIdx.x;
    int v = (i<nb) ? bsum[i] : 0;
    sh[threadIdx.x]=v;
    __syncthreads();
    for(int o=1;o<256;o<<=1){
      int t = (threadIdx.x>=o) ? sh[threadIdx.x-o] : 0;
      __syncthreads();
      sh[threadIdx.x]+=t;
      __syncthreads();
    }
    int incl = sh[threadIdx.x];
    int c = carry;
    if(i<nb) bsum[i] = incl - v + c;
    __syncthreads();
    if(threadIdx.x==255) carry = c + incl;
    __syncthreads();
  }
}

// rowptr[i] = exclusive scan of degi (+ block offset); also cursor copy and dinv
__global__ void scan_local(const int* __restrict__ degi, const int* __restrict__ bofs,
                           int n, int* __restrict__ rowptr, int* __restrict__ cursor,
                           float* __restrict__ dinv){
  __shared__ int sh[256];
  int i = blockIdx.x*256 + threadIdx.x;
  int v = (i<n) ? degi[i] : 0;
  sh[threadIdx.x]=v;
  __syncthreads();
  for(int o=1;o<256;o<<=1){
    int t = (threadIdx.x>=o) ? sh[threadIdx.x-o] : 0;
    __syncthreads();
    sh[threadIdx.x]+=t;
    __syncthreads();
  }
  if(i<n){
    int excl = sh[threadIdx.x] - v + bofs[blockIdx.x];
    rowptr[i]=excl; cursor[i]=excl;
    dinv[i] = rsqrtf((float)v + 1.0f);
  }
}

__global__ void csr_fill(const int* __restrict__ src, const int* __restrict__ dst,
                         const int* __restrict__ cnt, int m_static,
                         int* __restrict__ cursor, int* __restrict__ csr){
  int m = cnt ? cnt[0] : m_static;
  int stride = gridDim.x*blockDim.x;
  for(int e = blockIdx.x*blockDim.x+threadIdx.x; e<m; e+=stride){
    int pos = atomicAdd(&cursor[dst[e]], 1);
    csr[pos] = src[e];
  }
}

// g[d, q..q+3] = dinv[d]*( h[d]*dinv[d] + sum_{s in N(d)} h[s]*dinv[s] ), float4 per thread
__global__ void csr_gather4(const float* __restrict__ h, const float* __restrict__ dinv,
                            const int* __restrict__ rowptr, const int* __restrict__ degi,
                            const int* __restrict__ csr, float* __restrict__ g,
                            int n, int Fi, int qshift){
  long long t = (long long)blockIdx.x*blockDim.x + threadIdx.x;
  int d = (int)(t >> qshift);
  if(d>=n) return;
  int q = ((int)t & ((1<<qshift)-1)) << 2;
  int start = rowptr[d], deg = degi[d];
  float di = dinv[d];
  float4 hv = *(const float4*)(h + (size_t)d*Fi + q);
  float4 acc = make_float4(hv.x*di, hv.y*di, hv.z*di, hv.w*di);
  for(int j=0;j<deg;j++){
    int s = csr[start+j];
    float ds = dinv[s];
    float4 hs = *(const float4*)(h + (size_t)s*Fi + q);
    acc.x = fmaf(hs.x, ds, acc.x);
    acc.y = fmaf(hs.y, ds, acc.y);
    acc.z = fmaf(hs.z, ds, acc.z);
    acc.w = fmaf(hs.w, ds, acc.w);
  }
  *(float4*)(g + (size_t)d*Fi + q) = make_float4(acc.x*di, acc.y*di, acc.z*di, acc.w*di);
}

// ---------------- LDS-tiled fused dense: hfull = relu(g@W+b); score = tanh(hfull.p/||p||) ----
// Block: 256 threads. BM = 8192/Fo rows staged in LDS (<=16KB). Thread owns one output
// column c for 32 rows (group g of 256/Fo). h read back as same-address LDS broadcast
// (conflict-free); per K-quad per thread: 4 coalesced W loads + 32 ds_read_b128 + 128 FMA.
__global__ void matmul_relu_score_t(const float* __restrict__ h, const float* __restrict__ W,
                                    const float* __restrict__ b, const float* __restrict__ p,
                                    float* __restrict__ out, float* __restrict__ score,
                                    int n, int Fi, int Fo, int foshf, int BM, int qsh){
  __shared__ float lh[4096];     // [BM][Fi], BM*Fi <= 4096
  __shared__ float sp[8][32];
  __shared__ float pn_sh;
  int tid = threadIdx.x;
  // ||p||^-1 by wave 0
  if(tid < 64){
    float s=0.f;
    for(int f=tid; f<Fo; f+=64) s += p[f]*p[f];
    for(int o=32;o;o>>=1) s += __shfl_down(s,o,64);
    if(tid==0) pn_sh = rsqrtf(s);
  }
  int rb = blockIdx.x*BM;
  int fq = Fi>>2;
  int total_q = BM*fq;
  for(int idx=tid; idx<total_q; idx+=256){
    int row = idx>>qsh, q = idx & (fq-1);
    float4 v = make_float4(0.f,0.f,0.f,0.f);
    if(rb+row < n) v = *(const float4*)(h + (size_t)(rb+row)*Fi + q*4);
    *(float4*)(lh + (size_t)row*Fi + q*4) = v;
  }
  __syncthreads();
  int c = tid & (Fo-1);
  int g = tid >> foshf;     // row group, 256/Fo groups x 32 rows
  int r0 = g << 5;
  float acc[32];
  #pragma unroll
  for(int j=0;j<32;j++) acc[j]=0.f;
  for(int i=0;i<Fi;i+=4){
    float w0=W[(size_t)i*Fo+c],     w1=W[(size_t)(i+1)*Fo+c];
    float w2=W[(size_t)(i+2)*Fo+c], w3=W[(size_t)(i+3)*Fo+c];
    const float* lp = lh + (size_t)r0*Fi + i;
    #pragma unroll
    for(int j=0;j<32;j++){
      float4 hv = *(const float4*)(lp + (size_t)j*Fi);
      acc[j] = fmaf(hv.x,w0, fmaf(hv.y,w1, fmaf(hv.z,w2, fmaf(hv.w,w3, acc[j]))));
    }
  }
  float bc = b[c], pc = p[c];
  int width  = (Fo < 64) ? Fo : 64;
  int wsplit = (Fo >= 64) ? (Fo>>6) : 1;
  int slot = g*wsplit + (c>>6);
  #pragma unroll
  for(int j=0;j<32;j++){
    float v = acc[j] + bc;
    v = v>0.f ? v : 0.f;
    int row = rb + r0 + j;
    if(row < n) out[(size_t)row*Fo + c] = v;
    float sc = v*pc;
    for(int o=width>>1; o; o>>=1) sc += __shfl_down(sc, o, width);
    if((c & 63)==0) sp[slot][j] = sc;
  }
  __syncthreads();
  if(tid < BM){
    int j = tid, gg = j>>5;
    float s2 = 0.f;
    for(int ws=0; ws<wsplit; ws++) s2 += sp[gg*wsplit+ws][j&31];
    int row = rb + j;
    if(row < n) score[row] = tanhf(s2 * pn_sh);
  }
}

// ---------------- grid-wide two-level 16-bit top-k select ----------------
__global__ void hist_hi(const float* __restrict__ score, int n, int* __restrict__ ghist){
  int T = gridDim.x*blockDim.x;
  int lane = threadIdx.x&63;
  for(int base=0; base<n; base+=T){
    int i = base + blockIdx.x*blockDim.x + threadIdx.x;
    bool act = i<n;
    unsigned key = act ? (ordf(score[i])>>16) : 0u;
    unsigned long long eq = __ballot(act);
    #pragma unroll
    for(int bit=0;bit<16;bit++){
      unsigned long long bb = __ballot(act && ((key>>bit)&1u));
      eq &= ((key>>bit)&1u) ? bb : ~bb;
    }
    if(act){
      int lead = __ffsll(eq)-1;
      if(lane==lead) atomicAdd(&ghist[key], __popcll(eq));
    }
  }
}

__global__ void hist_lo(const float* __restrict__ score, int n,
                        const unsigned* __restrict__ selhi, int* __restrict__ ghist){
  unsigned hi = selhi[0];
  int T = gridDim.x*blockDim.x;
  int lane = threadIdx.x&63;
  for(int base=0; base<n; base+=T){
    int i = base + blockIdx.x*blockDim.x + threadIdx.x;
    unsigned o = (i<n) ? ordf(score[i]) : 0u;
    bool act = (i<n) && ((o>>16)==hi);
    unsigned key = o & 0xFFFFu;
    unsigned long long eq = __ballot(act);
    #pragma unroll
    for(int bit=0;bit<16;bit++){
      unsigned long long bb = __ballot(act && ((key>>bit)&1u));
      eq &= ((key>>bit)&1u) ? bb : ~bb;
    }
    if(act){
      int lead = __ffsll(eq)-1;
      if(lane==lead) atomicAdd(&ghist[key], __popcll(eq));
    }
  }
}

// scan 65536-bin histogram in DESCENDING key order; find crossing of rank
__global__ void find_sel(const int* __restrict__ hist, const int* __restrict__ rank_in,
                         int rank_static, const unsigned* __restrict__ hi_in,
                         unsigned* __restrict__ out_sel, int* __restrict__ out_rank){
  __shared__ int sh[1024];
  int t = threadIdx.x;
  int rank = rank_in ? rank_in[0] : rank_static;
  int base = t*64;
  int s = 0;
  for(int u=0;u<64;u++) s += hist[65535-(base+u)];
  sh[t]=s;
  __syncthreads();
  for(int o=1;o<1024;o<<=1){
    int tv = (t>=o)?sh[t-o]:0;
    __syncthreads();
    sh[t]+=tv;
    __syncthreads();
  }
  int excl = sh[t]-s;
  if(excl < rank && rank <= excl+s){
    for(int u=0;u<64;u++){
      int c = hist[65535-(base+u)];
      if(excl + c >= rank){
        unsigned key = (unsigned)(65535-(base+u));
        out_sel[0] = hi_in ? ((hi_in[0]<<16)|key) : key;
        out_rank[0] = rank - excl;
        break;
      }
      excl += c;
    }
  }
}

// ---------------- selection compaction ----------------

__global__ void sel_blockcount(const float* __restrict__ score, int n,
                               const unsigned* __restrict__ thr,
                               int* __restrict__ blkGt, int* __restrict__ blkEq){
  int i = blockIdx.x*256 + threadIdx.x;
  unsigned vthr = thr[0];
  int gt=0, eq=0;
  if(i<n){ unsigned o=ordf(score[i]); gt = (o>vthr); eq = (o==vthr); }
  unsigned long long bg=__ballot(gt), be=__ballot(eq);
  __shared__ int sg[4], se[4];
  int lane=threadIdx.x&63, w=threadIdx.x>>6;
  if(lane==0){ sg[w]=__popcll(bg); se[w]=__popcll(be); }
  __syncthreads();
  if(threadIdx.x==0){
    int g=0,e=0;
    for(int j=0;j<4;j++){ g+=sg[j]; e+=se[j]; }
    blkGt[blockIdx.x]=g; blkEq[blockIdx.x]=e;
  }
}

__global__ void scan_pair(int* __restrict__ blkGt, int* __restrict__ blkEq, int nb){
  __shared__ int shg[256], she[256];
  __shared__ int cg, ce;
  if(threadIdx.x==0){ cg=0; ce=0; }
  __syncthreads();
  for(int base=0;base<nb;base+=256){
    int i = base+threadIdx.x;
    int vg = (i<nb)?blkGt[i]:0;
    int ve = (i<nb)?blkEq[i]:0;
    shg[threadIdx.x]=vg; she[threadIdx.x]=ve;
    __syncthreads();
    for(int o=1;o<256;o<<=1){
      int tg = (threadIdx.x>=o)?shg[threadIdx.x-o]:0;
      int te = (threadIdx.x>=o)?she[threadIdx.x-o]:0;
      __syncthreads();
      shg[threadIdx.x]+=tg; she[threadIdx.x]+=te;
      __syncthreads();
    }
    int ig = shg[threadIdx.x], ie = she[threadIdx.x];
    int c0=cg, c1=ce;
    if(i<nb){ blkGt[i]=ig-vg+c0; blkEq[i]=ie-ve+c1; }
    __syncthreads();
    if(threadIdx.x==255){ cg=c0+ig; ce=c1+ie; }
    __syncthreads();
  }
}

__global__ void compact(const float* __restrict__ score, int n,
                        const unsigned* __restrict__ thr, const int* __restrict__ qp,
                        const int* __restrict__ blkGt, const int* __restrict__ blkEq,
                        int* __restrict__ newidx, int* __restrict__ oldidx){
  int i = blockIdx.x*256 + threadIdx.x;
  unsigned vthr = thr[0];
  int q = qp[0];
  int gt=0, eq=0;
  if(i<n){ unsigned o=ordf(score[i]); gt=(o>vthr); eq=(o==vthr); }
  unsigned long long bg=__ballot(gt), be=__ballot(eq);
  int lane=threadIdx.x&63, w=threadIdx.x>>6;
  unsigned long long mask = lane ? (~0ull >> (64-lane)) : 0ull;
  int pg = __popcll(bg & mask), pe = __popcll(be & mask);
  __shared__ int sg[4], se[4];
  if(lane==63){ sg[w]=pg+gt; se[w]=pe+eq; }
  __syncthreads();
  int wg=0,we=0;
  for(int j=0;j<w;j++){ wg+=sg[j]; we+=se[j]; }
  if(i<n){
    int gtp = blkGt[blockIdx.x] + wg + pg;
    int eqp = blkEq[blockIdx.x] + we + pe;
    int sel = gt || (eq && (eqp < q));
    if(sel){
      int pos = gtp + (eqp < q ? eqp : q);  // rank among selected, by original index
      newidx[i]=pos; oldidx[pos]=i;
    } else newidx[i]=-1;
  }
}

// hout[nr, q..q+3] = hfull[old, q..q+3] * score[old], float4 per thread
__global__ void gather_scale4(const float* __restrict__ hfull, const float* __restrict__ score,
                              const int* __restrict__ oldidx, float* __restrict__ hout,
                              int k, int Fo, int foshf){
  long long t = (long long)blockIdx.x*blockDim.x + threadIdx.x;
  int nr = (int)(t >> (foshf-2));
  if(nr >= k) return;
  int q = ((int)t & ((Fo>>2)-1)) << 2;
  int old = oldidx[nr];
  float s = score[old];
  float4 v = *(const float4*)(hfull + (size_t)old*Fo + q);
  *(float4*)(hout + (size_t)nr*Fo + q) = make_float4(v.x*s, v.y*s, v.z*s, v.w*s);
}

// ---------------- scan-based edge compaction ----------------

__global__ void edge_valid_count(const int* __restrict__ src, const int* __restrict__ dst,
                                 const int* __restrict__ cnt_in, int m_static,
                                 const int* __restrict__ newidx, int* __restrict__ bcnt){
  int m = cnt_in ? cnt_in[0] : m_static;
  int i = blockIdx.x*256 + threadIdx.x;
  int v = 0;
  if(i<m) v = (newidx[src[i]]>=0 && newidx[dst[i]]>=0);
  unsigned long long b = __ballot(v);
  __shared__ int sg[4];
  int lane=threadIdx.x&63, w=threadIdx.x>>6;
  if(lane==0) sg[w]=__popcll(b);
  __syncthreads();
  if(threadIdx.x==0) bcnt[blockIdx.x]=sg[0]+sg[1]+sg[2]+sg[3];
}

__global__ void edge_scan(int* __restrict__ bcnt, int nb, int* __restrict__ cnt_out){
  __shared__ int sh[256];
  __shared__ int carry;
  if(threadIdx.x==0) carry=0;
  __syncthreads();
  for(int base=0;base<nb;base+=256){
    int i = base+threadIdx.x;
    int v = (i<nb) ? bcnt[i] : 0;
    sh[threadIdx.x]=v;
    __syncthreads();
    for(int o=1;o<256;o<<=1){
      int t = (threadIdx.x>=o) ? sh[threadIdx.x-o] : 0;
      __syncthreads();
      sh[threadIdx.x]+=t;
      __syncthreads();
    }
    int incl = sh[threadIdx.x];
    int c = carry;
    if(i<nb) bcnt[i] = incl - v + c;
    __syncthreads();
    if(threadIdx.x==255) carry = c + incl;
    __syncthreads();
  }
  if(threadIdx.x==0) cnt_out[0]=carry;
}

// writes compacted edges AND accumulates next-layer in-degree (folds deg_count pass)
__global__ void edge_write_deg(const int* __restrict__ src, const int* __restrict__ dst,
                               const int* __restrict__ cnt_in, int m_static,
                               const int* __restrict__ newidx, const int* __restrict__ bofs,
                               int* __restrict__ osrc, int* __restrict__ odst,
                               int* __restrict__ degi_next){
  int m = cnt_in ? cnt_in[0] : m_static;
  int i = blockIdx.x*256 + threadIdx.x;
  int v=0, ns=0, nd=0;
  if(i<m){
    ns = newidx[src[i]]; nd = newidx[dst[i]];
    v = (ns>=0 && nd>=0);
  }
  unsigned long long b = __ballot(v);
  int lane=threadIdx.x&63, w=threadIdx.x>>6;
  unsigned long long mask = lane ? (~0ull >> (64-lane)) : 0ull;
  int p = __popcll(b & mask);
  __shared__ int sg[4];
  if(lane==63) sg[w]=p+v;
  __syncthreads();
  int wofs=0;
  for(int j=0;j<w;j++) wofs+=sg[j];
  if(v){
    int pos = bofs[blockIdx.x] + wofs + p;
    osrc[pos]=ns; odst[pos]=nd;
    atomicAdd(&degi_next[nd], 1);
  }
}

// ---------------- epilogue ----------------

__global__ void pool_kernel(const float* __restrict__ h, int n, float* __restrict__ xc){
  int f = blockIdx.x;
  float mx = -3.402823466e38f, sm=0.f;
  for(int r=threadIdx.x; r<n; r+=blockDim.x){
    float v = h[(size_t)r*256+f];
    mx = fmaxf(mx,v); sm += v;
  }
  __shared__ float smx[4], ssm[4];
  for(int o=32;o;o>>=1){ mx=fmaxf(mx,__shfl_down(mx,o,64)); sm+=__shfl_down(sm,o,64); }
  int lane=threadIdx.x&63, w=threadIdx.x>>6;
  if(lane==0){ smx[w]=mx; ssm[w]=sm; }
  __syncthreads();
  if(threadIdx.x==0){
    for(int j=1;j<4;j++){ mx=fmaxf(mx,smx[j]); sm+=ssm[j]; }
    xc[f]=mx; xc[256+f]=sm/(float)n;
  }
}

__global__ void fc_kernel(const float* __restrict__ xc, const float* __restrict__ fcw,
                          const float* __restrict__ fcb, const float* __restrict__ fc2w,
                          const float* __restrict__ fc2b, float* __restrict__ out){
  __shared__ float x[512];
  for(int i=threadIdx.x;i<512;i+=256) x[i]=xc[i];
  __syncthreads();
  int j=threadIdx.x;
  float a=fcb[j];
  for(int i=0;i<512;i++) a = fmaf(x[i], fcw[(size_t)j*512+i], a);
  a = a>0.f ? a : 0.f;
  float v = a*fc2w[j];
  for(int o=32;o;o>>=1) v += __shfl_down(v,o,64);
  __shared__ float sv[4];
  int lane=threadIdx.x&63, w=threadIdx.x>>6;
  if(lane==0) sv[w]=v;
  __syncthreads();
  if(threadIdx.x==0) out[0]=sv[0]+sv[1]+sv[2]+sv[3]+fc2b[0];
}

extern "C" void kernel_launch(void* const* d_in, const int* in_sizes, int n_in,
                              void* d_out, int out_size, void* d_ws, size_t ws_size,
                              hipStream_t stream) {
  const float* x   = (const float*)d_in[0];
  const int*   ei  = (const int*)d_in[1];
  const float* Wm[4] = {(const float*)d_in[2],(const float*)d_in[5],(const float*)d_in[8],(const float*)d_in[11]};
  const float* bv[4] = {(const float*)d_in[3],(const float*)d_in[6],(const float*)d_in[9],(const float*)d_in[12]};
  const float* pv[4] = {(const float*)d_in[4],(const float*)d_in[7],(const float*)d_in[10],(const float*)d_in[13]};
  const float* fcw  = (const float*)d_in[14];
  const float* fcb  = (const float*)d_in[15];
  const float* fc2w = (const float*)d_in[16];
  const float* fc2b = (const float*)d_in[17];

  char* base = (char*)d_ws; size_t off=0;
  auto alloc = [&](size_t bytes)->void*{
    void* p = base + off; off += (bytes + 511) & ~(size_t)511; return p;
  };
  int*   es1    = (int*)  alloc((size_t)NE*4);
  int*   ed1    = (int*)  alloc((size_t)NE*4);
  int*   es2    = (int*)  alloc((size_t)NE*4);
  int*   ed2    = (int*)  alloc((size_t)NE*4);
  int*   csr    = (int*)  alloc((size_t)NE*4);
  int*   degi   = (int*)  alloc((size_t)NV*4);
  int*   rowptr = (int*)  alloc((size_t)NV*4);
  int*   cursor = (int*)  alloc((size_t)NV*4);
  float* dinv   = (float*)alloc((size_t)NV*4);
  float* score  = (float*)alloc((size_t)NV*4);
  int*   newidx = (int*)  alloc((size_t)NV*4);
  int*   oldidx = (int*)  alloc((size_t)NV*4);
  float* g      = (float*)alloc((size_t)2621568*4);
  float* hfull  = (float*)alloc((size_t)5243136*4);
  float* hbuf   = (float*)alloc((size_t)2621696*4);
  int*   ghist  = (int*)  alloc((size_t)131072*4);
  int*   bsum   = (int*)  alloc(4096);
  int*   ebcnt  = (int*)  alloc((size_t)NBE*4+512);
  int*   cnt    = (int*)  alloc(64);
  unsigned* thr = (unsigned*)alloc(64);
  int*   qv     = (int*)  alloc(64);
  unsigned* selhi = (unsigned*)alloc(64);
  int*   rank2  = (int*)  alloc(64);
  int*   blkGt  = (int*)  alloc(4096);
  int*   blkEq  = (int*)  alloc(4096);
  float* xc     = (float*)alloc(2048);
  if (off > ws_size) return;

  const int ns[5]   = {163842, 81921, 40961, 20481, 10241};
  const int dims[5] = {4, 32, 64, 128, 256};
  const int foshf[4]= {5, 6, 7, 8};     // log2(Fo)
  const int qshf[4] = {0, 3, 4, 5};     // log2(Fi/4)

  const int* curS[4] = {ei,      es1, es2, es1};
  const int* curD[4] = {ei + NE, ed1, ed2, ed1};
  int*       outS[3] = {es1, es2, es1};
  int*       outD[3] = {ed1, ed2, ed1};

  const float* hin = x;
  for(int l=0;l<4;l++){
    int n=ns[l], k=ns[l+1], Fi=dims[l], Fo=dims[l+1];
    const int* cin = (l==0) ? nullptr : (cnt + (l-1));
    int nb = (n+255)/256;
    unsigned egrid = (l==0) ? 2048 : 1024;
    // ---- CSR build (degi for l>0 already produced by previous edge_write_deg) ----
    if(l==0){
      hipMemsetAsync(degi, 0, (size_t)n*4, stream);
      deg_count<<<egrid,256,0,stream>>>(curD[l], cin, NE, degi);
    }
    block_sums<<<nb,256,0,stream>>>(degi, n, bsum);
    scan_bsums<<<1,256,0,stream>>>(bsum, nb);
    scan_local<<<nb,256,0,stream>>>(degi, bsum, n, rowptr, cursor, dinv);
    csr_fill<<<egrid,256,0,stream>>>(curS[l], curD[l], cin, NE, cursor, csr);
    // ---- aggregation (gather, float4, no atomics) ----
    long long nq = (long long)n << qshf[l];
    csr_gather4<<<(unsigned)((nq+255)/256),256,0,stream>>>(hin, dinv, rowptr, degi, csr, g, n, Fi, qshf[l]);
    // ---- LDS-tiled fused dense + score ----
    int BM = 8192 >> foshf[l];
    unsigned mgrid = (unsigned)((n + BM - 1) / BM);
    matmul_relu_score_t<<<mgrid,256,0,stream>>>(g, Wm[l], bv[l], pv[l], hfull, score,
                                                n, Fi, Fo, foshf[l], BM, qshf[l]);
    // ---- top-k selection (grid-wide two-level 16-bit select) ----
    hipMemsetAsync(ghist, 0, (size_t)131072*4, stream);
    hist_hi<<<256,256,0,stream>>>(score, n, ghist);
    find_sel<<<1,1024,0,stream>>>(ghist, nullptr, k, nullptr, selhi, rank2);
    hist_lo<<<256,256,0,stream>>>(score, n, selhi, ghist+65536);
    find_sel<<<1,1024,0,stream>>>(ghist+65536, rank2, 0, selhi, thr, qv);
    // ---- compaction ----
    sel_blockcount<<<nb,256,0,stream>>>(score, n, thr, blkGt, blkEq);
    scan_pair<<<1,256,0,stream>>>(blkGt, blkEq, nb);
    compact<<<nb,256,0,stream>>>(score, n, thr, qv, blkGt, blkEq, newidx, oldidx);
    long long kq = (long long)k << (foshf[l]-2);
    gather_scale4<<<(unsigned)((kq+255)/256),256,0,stream>>>(hfull, score, oldidx, hbuf, k, Fo, foshf[l]);
    // ---- edge compaction for next layer (also builds next-layer degree) ----
    if(l<3){
      hipMemsetAsync(degi, 0, (size_t)ns[l+1]*4, stream);
      edge_valid_count<<<NBE,256,0,stream>>>(curS[l], curD[l], cin, NE, newidx, ebcnt);
      edge_scan<<<1,256,0,stream>>>(ebcnt, NBE, cnt + l);
      edge_write_deg<<<NBE,256,0,stream>>>(curS[l], curD[l], cin, NE, newidx, ebcnt,
                                           outS[l], outD[l], degi);
    }
    hin = hbuf;
  }

  pool_kernel<<<256,256,0,stream>>>(hbuf, ns[4], xc);
  fc_kernel<<<1,256,0,stream>>>(xc, fcw, fcb, fc2w, fc2b, (float*)d_out);
}